// Round 4
// baseline (16112.912 us; speedup 1.0000x reference)
//
#include <hip/hip_runtime.h>
#include <hip/hip_bf16.h>

#define B_ 4
#define T_ 300
#define U_ 64
#define U1_ 65
#define V_ 1024
#define H_ 512
#define G4_ 2048
#define NW_ 32
#define RPB_ (T_ * U1_)   // 19500 rows per batch in joint
#define NTILE_ 305        // ceil(19500/64)
#define RPAD_ 19520       // NTILE_*64

typedef __hip_bfloat16 bf16;
typedef __attribute__((ext_vector_type(8))) short short8;
typedef __attribute__((ext_vector_type(4))) float floatx4;

__device__ __forceinline__ float b2f(bf16 x) { return __bfloat162float(x); }
__device__ __forceinline__ bf16 f2b(float x) { return __float2bfloat16(x); }
__device__ __forceinline__ short bf16bits(float x) {
  bf16 h = __float2bfloat16(x);
  return *reinterpret_cast<short*>(&h);
}
__device__ __forceinline__ short8 pack8(float4 a, float4 b) {
  short8 p;
  p[0] = bf16bits(a.x); p[1] = bf16bits(a.y); p[2] = bf16bits(a.z); p[3] = bf16bits(a.w);
  p[4] = bf16bits(b.x); p[5] = bf16bits(b.y); p[6] = bf16bits(b.z); p[7] = bf16bits(b.w);
  return p;
}
__device__ __forceinline__ float sigm_(float x) { return 1.f / (1.f + __expf(-x)); }
__device__ __forceinline__ float tanh_(float x) { return 1.f - 2.f / (1.f + __expf(2.f * x)); }
__device__ __forceinline__ float lae_(float x, float y) {
  float m = fmaxf(x, y);
  float n = fminf(x, y);
  return m + __logf(1.f + __expf(n - m));
}

// ---------------- prep: pad layer-0 input (80 -> 128 cols of a 1024-stride buf), zero barriers
__global__ void prep_kernel(const float* __restrict__ in, bf16* __restrict__ x0, int* __restrict__ bars) {
  int i = blockIdx.x * 256 + threadIdx.x;
  if (i < B_ * T_ * 128) {
    int k = i & 127;
    int row = i >> 7;
    float v = (k < 80) ? in[row * 80 + k] : 0.f;
    x0[(size_t)row * 1024 + k] = f2b(v);
  }
  if (blockIdx.x == 0 && threadIdx.x < 32) bars[threadIdx.x] = 0;
}

// ---------------- embedding gather (f32 table -> bf16)
__global__ void embed_kernel(const float* __restrict__ emb, const int* __restrict__ tgt,
                             bf16* __restrict__ demb) {
  int i = blockIdx.x * 256 + threadIdx.x;
  if (i >= B_ * U1_ * 512) return;
  int k = i & 511;
  int bu = i >> 9;
  int u = bu % U1_, b = bu / U1_;
  int id = (u == 0) ? 0 : tgt[b * U_ + u - 1];
  demb[i] = f2b(emb[(size_t)id * 512 + k]);
}

// ---------------- bf16-A x f32-W MFMA GEMM: C[M x (grid.y*64)] = A[M,K] @ W[N,K]^T + bias
__global__ __launch_bounds__(256) void gemm_kernel(
    const bf16* __restrict__ A, int lda,
    const float* __restrict__ W, int ldw,
    const float* __restrict__ bias,
    void* __restrict__ Cout, int out_f32, int ldc,
    int M, int K) {
  __shared__ __align__(16) bf16 As[64][72];
  __shared__ __align__(16) bf16 Bs[64][72];
  int m0 = blockIdx.x * 64, n0 = blockIdx.y * 64;
  int tid = threadIdx.x, w = tid >> 6, l = tid & 63;
  int l4 = l & 15, lq = l >> 4;
  floatx4 acc[4];
#pragma unroll
  for (int nt = 0; nt < 4; ++nt) acc[nt] = (floatx4){0.f, 0.f, 0.f, 0.f};
  for (int k0 = 0; k0 < K; k0 += 64) {
    __syncthreads();
#pragma unroll
    for (int q = 0; q < 2; ++q) {
      int cc = tid + q * 256;
      int r = cc >> 3, kc = (cc & 7) * 8;
      short8 va = {0, 0, 0, 0, 0, 0, 0, 0};
      int gm = m0 + r;
      if (gm < M) va = *(const short8*)(A + (size_t)gm * lda + k0 + kc);
      *(short8*)(&As[r][kc]) = va;
      const float* wp = W + (size_t)(n0 + r) * ldw + k0 + kc;
      float4 w0 = *(const float4*)(wp);
      float4 w1 = *(const float4*)(wp + 4);
      *(short8*)(&Bs[r][kc]) = pack8(w0, w1);
    }
    __syncthreads();
#pragma unroll
    for (int kk = 0; kk < 64; kk += 32) {
      short8 a = *(const short8*)(&As[w * 16 + l4][kk + lq * 8]);
#pragma unroll
      for (int nt = 0; nt < 4; ++nt) {
        short8 bb = *(const short8*)(&Bs[nt * 16 + l4][kk + lq * 8]);
        acc[nt] = __builtin_amdgcn_mfma_f32_16x16x32_bf16(a, bb, acc[nt], 0, 0, 0);
      }
    }
  }
#pragma unroll
  for (int nt = 0; nt < 4; ++nt) {
    int col = n0 + nt * 16 + l4;
    float bv = bias ? bias[col] : 0.f;
#pragma unroll
    for (int r = 0; r < 4; ++r) {
      int row = m0 + w * 16 + lq * 4 + r;
      if (row < M) {
        float v = acc[nt][r] + bv;
        if (out_f32) ((float*)Cout)[(size_t)row * ldc + col] = v;
        else ((bf16*)Cout)[(size_t)row * ldc + col] = f2b(v);
      }
    }
  }
}

// ---------------- cross-WG barrier (one per dir-group of NW_ WGs)
__device__ __forceinline__ void group_barrier(int* bar) {
  __syncthreads();
  if (threadIdx.x == 0) {
    int g = __hip_atomic_load(bar + 1, __ATOMIC_ACQUIRE, __HIP_MEMORY_SCOPE_AGENT);
    int c = __hip_atomic_fetch_add(bar, 1, __ATOMIC_ACQ_REL, __HIP_MEMORY_SCOPE_AGENT);
    if (c == NW_ - 1) {
      __hip_atomic_store(bar, 0, __ATOMIC_RELAXED, __HIP_MEMORY_SCOPE_AGENT);
      __hip_atomic_store(bar + 1, g + 1, __ATOMIC_RELEASE, __HIP_MEMORY_SCOPE_AGENT);
    } else {
      while (__hip_atomic_load(bar + 1, __ATOMIC_ACQUIRE, __HIP_MEMORY_SCOPE_AGENT) == g) {
        __builtin_amdgcn_s_sleep(2);
      }
    }
  }
  __syncthreads();
}

// ---------------- persistent LSTM scan. grid = (NW_, ndir). WG w owns h-dims [w*16, w*16+16)
__global__ __launch_bounds__(256, 1) void scan_kernel(
    const float* __restrict__ xg,      // [ndir][B][Tmax][2048] f32
    const float* __restrict__ whh,     // [ndir][2048][512] f32
    const int* __restrict__ len_raw, int len_add,
    int Tmax, int bwd_mask,
    bf16* __restrict__ out, int out_stride,
    float* __restrict__ h_buf,         // [2][2][B][512] f32
    int* __restrict__ bars) {
  int w = blockIdx.x, d = blockIdx.y;
  int tid = threadIdx.x;
  const float* xg_d = xg + (size_t)d * B_ * Tmax * G4_;
  const float* whh_d = whh + (size_t)d * G4_ * H_;
  int* bar = bars + d * 2;
  bool bwd = (bwd_mask >> d) & 1;

  int row = tid & 63;          // gate = row>>4, dim = row&15
  int ks = tid >> 6;           // k-slice 0..3 (128 each)
  int grow = (row >> 4) * H_ + w * 16 + (row & 15);

  float wreg[128];
  {
    const float* wp = whh_d + (size_t)grow * H_ + ks * 128;
#pragma unroll
    for (int j = 0; j < 128; ++j) wreg[j] = wp[j];
  }

  __shared__ float h_lds[4][512];
  __shared__ float partial[4][64][5];
  __shared__ float gates[64][5];
  __shared__ float c_lds[16][4];
  __shared__ int len_s[4];

  if (tid < 4) len_s[tid] = len_raw[tid] + len_add;
  if (tid < 64) c_lds[tid & 15][tid >> 4] = 0.f;
  __syncthreads();
  int smax = max(max(len_s[0], len_s[1]), max(len_s[2], len_s[3]));

  if (tid < 64) {
    int dim = tid & 15, bb = tid >> 4;
    h_buf[((size_t)d * B_ + bb) * H_ + w * 16 + dim] = 0.f;
  }
  __threadfence();
  group_barrier(bar);

  int rb = tid >> 6;
  for (int s = 0; s < smax; ++s) {
    const float* hrd = h_buf + (size_t)((s & 1) * 2 + d) * B_ * H_;
    float* hwr = h_buf + (size_t)(((s + 1) & 1) * 2 + d) * B_ * H_;
#pragma unroll
    for (int q = 0; q < 8; ++q) {
      int i = tid + q * 256;
      h_lds[i >> 9][i & 511] = hrd[i];
    }
    bool ract = s < len_s[rb];
    int rt = bwd ? (len_s[rb] - 1 - s) : s;
    if (!ract) rt = 0;
    float xv = xg_d[((size_t)rb * Tmax + rt) * G4_ + grow];
    __syncthreads();
    float a0 = 0.f, a1 = 0.f, a2 = 0.f, a3 = 0.f;
    {
      int kb = ks * 128;
#pragma unroll
      for (int j = 0; j < 128; ++j) {
        float wv = wreg[j];
        a0 = __builtin_fmaf(wv, h_lds[0][kb + j], a0);
        a1 = __builtin_fmaf(wv, h_lds[1][kb + j], a1);
        a2 = __builtin_fmaf(wv, h_lds[2][kb + j], a2);
        a3 = __builtin_fmaf(wv, h_lds[3][kb + j], a3);
      }
    }
    partial[ks][row][0] = a0;
    partial[ks][row][1] = a1;
    partial[ks][row][2] = a2;
    partial[ks][row][3] = a3;
    __syncthreads();
    gates[row][rb] = partial[0][row][rb] + partial[1][row][rb] +
                     partial[2][row][rb] + partial[3][row][rb] + xv;
    __syncthreads();
    if (tid < 64) {
      int dim = tid & 15, bb = tid >> 4;
      if (s < len_s[bb]) {
        float gi = gates[dim][bb];
        float gf = gates[16 + dim][bb];
        float gg = gates[32 + dim][bb];
        float go = gates[48 + dim][bb];
        float c = c_lds[dim][bb];
        c = sigm_(gf) * c + sigm_(gi) * tanh_(gg);
        float h = sigm_(go) * tanh_(c);
        c_lds[dim][bb] = c;
        int t = bwd ? (len_s[bb] - 1 - s) : s;
        hwr[(size_t)bb * H_ + w * 16 + dim] = h;
        out[((size_t)bb * Tmax + t) * out_stride + d * H_ + w * 16 + dim] = f2b(h);
      }
    }
    __threadfence();
    group_barrier(bar);
  }
}

// ---------------- joint (<=48KB LDS): block = 64 rows x 256 cols, K=512.
__global__ __launch_bounds__(256) void joint_kernel(
    const float* __restrict__ ea, const float* __restrict__ da,
    const float* __restrict__ Wp, const float* __restrict__ pb,
    const int* __restrict__ targets,
    float* __restrict__ blankraw, float* __restrict__ labraw,
    float* __restrict__ jstats) {
  __shared__ __align__(16) bf16 As[64][72];
  __shared__ __align__(16) bf16 Bs[256][72];
  __shared__ float bias_s[256];
  __shared__ int tgt_s[64];
  __shared__ float pstat[64][2][2];

  int tid = threadIdx.x;
  int tile = blockIdx.x, cb = blockIdx.y, b = blockIdx.z;
  int r0 = tile * 64;

  bias_s[tid & 255] = pb[cb * 256 + (tid & 255)];
  if (tid < 64) {
    int r = r0 + tid;
    int u = r % U1_;
    tgt_s[tid] = (r < RPB_ && u < U_) ? targets[b * U_ + u] : -1;
  }
  int si = tid >> 2;
  int sseg = (tid & 3) * 16;
  int sr = r0 + si;
  bool svalid = sr < RPB_;
  int st = svalid ? sr / U1_ : 0;
  int su = svalid ? sr % U1_ : 0;
  const float* ep = ea + ((size_t)(b * T_ + st)) * 512 + sseg;
  const float* dp = da + ((size_t)(b * U1_ + su)) * 512 + sseg;

  int wid = tid >> 6, l = tid & 63;
  int wm = wid >> 1, wn = wid & 1;
  int l4 = l & 15, lq = l >> 4;

  floatx4 acc[2][8];
#pragma unroll
  for (int ms = 0; ms < 2; ++ms)
#pragma unroll
    for (int nt = 0; nt < 8; ++nt) acc[ms][nt] = (floatx4){0.f, 0.f, 0.f, 0.f};

  for (int k0 = 0; k0 < 512; k0 += 64) {
    __syncthreads();
    {
      const float* e = ep + k0;
      const float* d = dp + k0;
#pragma unroll
      for (int h = 0; h < 2; ++h) {
        float4 e0 = *(const float4*)(e + h * 8);
        float4 e1 = *(const float4*)(e + h * 8 + 4);
        float4 d0 = *(const float4*)(d + h * 8);
        float4 d1 = *(const float4*)(d + h * 8 + 4);
        short8 pk = {0, 0, 0, 0, 0, 0, 0, 0};
        if (svalid) {
          pk[0] = bf16bits(tanh_(e0.x + d0.x));
          pk[1] = bf16bits(tanh_(e0.y + d0.y));
          pk[2] = bf16bits(tanh_(e0.z + d0.z));
          pk[3] = bf16bits(tanh_(e0.w + d0.w));
          pk[4] = bf16bits(tanh_(e1.x + d1.x));
          pk[5] = bf16bits(tanh_(e1.y + d1.y));
          pk[6] = bf16bits(tanh_(e1.z + d1.z));
          pk[7] = bf16bits(tanh_(e1.w + d1.w));
        }
        *(short8*)(&As[si][sseg + h * 8]) = pk;
      }
    }
#pragma unroll
    for (int q = 0; q < 8; ++q) {
      int cc = tid + q * 256;
      int r = cc >> 3, kc = (cc & 7) * 8;
      const float* wp = Wp + (size_t)(cb * 256 + r) * 512 + k0 + kc;
      float4 w0 = *(const float4*)(wp);
      float4 w1 = *(const float4*)(wp + 4);
      *(short8*)(&Bs[r][kc]) = pack8(w0, w1);
    }
    __syncthreads();
#pragma unroll
    for (int kk = 0; kk < 64; kk += 32) {
      short8 af[2], bf8[8];
#pragma unroll
      for (int ms = 0; ms < 2; ++ms)
        af[ms] = *(const short8*)(&As[wm * 32 + ms * 16 + l4][kk + lq * 8]);
#pragma unroll
      for (int nt = 0; nt < 8; ++nt)
        bf8[nt] = *(const short8*)(&Bs[wn * 128 + nt * 16 + l4][kk + lq * 8]);
#pragma unroll
      for (int ms = 0; ms < 2; ++ms)
#pragma unroll
        for (int nt = 0; nt < 8; ++nt)
          acc[ms][nt] = __builtin_amdgcn_mfma_f32_16x16x32_bf16(af[ms], bf8[nt], acc[ms][nt], 0, 0, 0);
    }
  }
#pragma unroll
  for (int ms = 0; ms < 2; ++ms) {
#pragma unroll
    for (int r = 0; r < 4; ++r) {
      int i = wm * 32 + ms * 16 + lq * 4 + r;
      int grow = r0 + i;
      bool valid = grow < RPB_;
      int tg = tgt_s[i];
      float v[8];
      float mx = -1e30f;
#pragma unroll
      for (int nt = 0; nt < 8; ++nt) {
        int colc = wn * 128 + nt * 16 + l4;
        float x = acc[ms][nt][r] + bias_s[colc];
        v[nt] = x;
        mx = fmaxf(mx, x);
        int gcol = cb * 256 + colc;
        if (valid) {
          if (gcol == 0) blankraw[(size_t)b * RPB_ + grow] = x;
          if (gcol == tg) labraw[(size_t)b * RPB_ + grow] = x;
        }
      }
#pragma unroll
      for (int dd = 1; dd < 16; dd <<= 1) mx = fmaxf(mx, __shfl_xor(mx, dd, 64));
      float se = 0.f;
#pragma unroll
      for (int nt = 0; nt < 8; ++nt) se += __expf(v[nt] - mx);
#pragma unroll
      for (int dd = 1; dd < 16; dd <<= 1) se += __shfl_xor(se, dd, 64);
      if (l4 == 0) { pstat[i][wn][0] = mx; pstat[i][wn][1] = se; }
    }
  }
  __syncthreads();
  if (tid < 64) {
    float ma = pstat[tid][0][0], sa = pstat[tid][0][1];
    float mb = pstat[tid][1][0], sb = pstat[tid][1][1];
    float mc = fmaxf(ma, mb);
    float sc = sa * __expf(ma - mc) + sb * __expf(mb - mc);
    size_t o = (((size_t)b * RPAD_ + r0 + tid) * 4 + cb) * 2;
    jstats[o] = mc;
    jstats[o + 1] = sc;
  }
}

// ---------------- finalize: merge 4 col-block stats -> lse; convert raw logits to log-probs
__global__ void finalize_kernel(const float* __restrict__ jstats,
                                float* __restrict__ blank, float* __restrict__ lab) {
  int g = blockIdx.x * 256 + threadIdx.x;
  if (g >= B_ * RPB_) return;
  int b = g / RPB_, r = g % RPB_;
  const float* st = jstats + ((size_t)b * RPAD_ + r) * 8;
  float M = fmaxf(fmaxf(st[0], st[2]), fmaxf(st[4], st[6]));
  float s = st[1] * __expf(st[0] - M) + st[3] * __expf(st[2] - M) +
            st[5] * __expf(st[4] - M) + st[7] * __expf(st[6] - M);
  float lse = M + __logf(s);
  blank[g] -= lse;
  if ((r % U1_) < U_) lab[g] -= lse;
}

// ---------------- RNNT loss (OUTPUT IS FLOAT32)
__global__ void loss_kernel(const float* __restrict__ blank, const float* __restrict__ lab,
                            const int* __restrict__ Tl, const int* __restrict__ Ul,
                            float* __restrict__ outp) {
  int b = threadIdx.x >> 6;
  int l = threadIdx.x & 63;
  int TL = Tl[b], UL = Ul[b];
  float alpha_l = 0.f, alpha0 = 0.f;
  for (int t = 0; t < TL; ++t) {
    float a_u0, a_l1;
    if (t == 0) { a_u0 = 0.f; a_l1 = -1e30f; }
    else {
      const float* bl = blank + ((size_t)b * T_ + (t - 1)) * U1_;
      a_u0 = alpha0 + bl[0];
      a_l1 = alpha_l + bl[l + 1];
    }
    const float* lb = lab + ((size_t)b * T_ + t) * U1_;
    float C = lb[l];
#pragma unroll
    for (int dd = 1; dd < 64; dd <<= 1) {
      float o = __shfl_up(C, dd, 64);
      if (l >= dd) C += o;
    }
    float S = a_l1 - C;
#pragma unroll
    for (int dd = 1; dd < 64; dd <<= 1) {
      float o = __shfl_up(S, dd, 64);
      if (l >= dd) S = lae_(S, o);
    }
    alpha_l = C + lae_(a_u0, S);
    alpha0 = a_u0;
  }
  float av = (UL == 0) ? alpha0 : __shfl(alpha_l, UL - 1, 64);
  float ll = av + blank[((size_t)b * T_ + (TL - 1)) * U1_ + UL];
  __shared__ float lls[4];
  if (l == 0) lls[b] = ll;
  __syncthreads();
  if (threadIdx.x == 0) outp[0] = -0.25f * (lls[0] + lls[1] + lls[2] + lls[3]);
}

// ---------------- workspace layout (bytes)
static constexpr size_t OFF_XG = 0;                                        // f32 [2][4][300][2048]
static constexpr size_t OFF_XA = OFF_XG + (size_t)2 * B_ * T_ * G4_ * 4;   // bf16 [4][300][1024]
static constexpr size_t OFF_XB = OFF_XA + (size_t)B_ * T_ * 1024 * 2;
static constexpr size_t OFF_ENC = OFF_XB + (size_t)B_ * T_ * 1024 * 2;     // bf16 [4][300][512]
static constexpr size_t OFF_EA = OFF_ENC + (size_t)B_ * T_ * 512 * 2;      // f32
static constexpr size_t OFF_DEMB = OFF_EA + (size_t)B_ * T_ * 512 * 4;     // bf16
static constexpr size_t OFF_DXG = OFF_DEMB + (size_t)B_ * U1_ * 512 * 2;   // f32
static constexpr size_t OFF_DH = OFF_DXG + (size_t)B_ * U1_ * G4_ * 4;     // bf16
static constexpr size_t OFF_DEC = OFF_DH + (size_t)B_ * U1_ * 512 * 2;     // bf16
static constexpr size_t OFF_DA = OFF_DEC + (size_t)B_ * U1_ * 512 * 2;     // f32
static constexpr size_t OFF_BL = OFF_DA + (size_t)B_ * U1_ * 512 * 4;      // f32 [4][300][65]
static constexpr size_t OFF_LAB = OFF_BL + (size_t)B_ * T_ * U1_ * 4;
static constexpr size_t OFF_HBUF = OFF_LAB + (size_t)B_ * T_ * U1_ * 4;    // f32 [2][2][4][512]
static constexpr size_t OFF_BARS = OFF_HBUF + (size_t)2 * 2 * B_ * H_ * 4; // 32 ints
static constexpr size_t OFF_JST = OFF_BARS + 128;                          // f32 [4][19520][4][2]

extern "C" void kernel_launch(void* const* d_in, const int* in_sizes, int n_in,
                              void* d_out, int out_size, void* d_ws, size_t ws_size,
                              hipStream_t stream) {
  (void)in_sizes; (void)n_in; (void)out_size; (void)ws_size;
  const float* inputs = (const float*)d_in[0];
  const int* inputs_length = (const int*)d_in[1];
  const int* targets = (const int*)d_in[2];
  const int* targets_length = (const int*)d_in[3];
  const float* enc_Wih = (const float*)d_in[4];
  const float* enc_Whh = (const float*)d_in[5];
  const float* enc_b = (const float*)d_in[6];
  const float* enc_proj_W = (const float*)d_in[7];
  const float* enc_proj_b = (const float*)d_in[8];
  const float* dec_emb = (const float*)d_in[9];
  const float* dec_Wih = (const float*)d_in[10];
  const float* dec_Whh = (const float*)d_in[11];
  const float* dec_b = (const float*)d_in[12];
  const float* dec_proj_W = (const float*)d_in[13];
  const float* dec_proj_b = (const float*)d_in[14];
  const float* j_fwd_W = (const float*)d_in[15];
  const float* j_fwd_b = (const float*)d_in[16];
  const float* j_proj_W = (const float*)d_in[17];
  const float* j_proj_b = (const float*)d_in[18];

  char* ws = (char*)d_ws;
  float* xg = (float*)(ws + OFF_XG);
  bf16* xa = (bf16*)(ws + OFF_XA);
  bf16* xb = (bf16*)(ws + OFF_XB);
  bf16* encb = (bf16*)(ws + OFF_ENC);
  float* eab = (float*)(ws + OFF_EA);
  bf16* demb = (bf16*)(ws + OFF_DEMB);
  float* dxg = (float*)(ws + OFF_DXG);
  bf16* dh = (bf16*)(ws + OFF_DH);
  bf16* decb = (bf16*)(ws + OFF_DEC);
  float* dab = (float*)(ws + OFF_DA);
  float* blank = (float*)(ws + OFF_BL);
  float* lab = (float*)(ws + OFF_LAB);
  float* hbuf = (float*)(ws + OFF_HBUF);
  int* bars = (int*)(ws + OFF_BARS);
  float* jstats = (float*)(ws + OFF_JST);

  prep_kernel<<<600, 256, 0, stream>>>(inputs, xa, bars);
  embed_kernel<<<520, 256, 0, stream>>>(dec_emb, targets, demb);

  // decoder chain
  gemm_kernel<<<dim3(5, 32), 256, 0, stream>>>(demb, 512, dec_Wih, 512, dec_b,
                                               dxg, 1, G4_, B_ * U1_, 512);
  scan_kernel<<<dim3(NW_, 1), 256, 0, stream>>>(dxg, dec_Whh, targets_length, 1, U1_, 0,
                                                dh, 512, hbuf, bars);
  gemm_kernel<<<dim3(5, 8), 256, 0, stream>>>(dh, 512, dec_proj_W, 512, dec_proj_b,
                                              decb, 0, 512, B_ * U1_, 512);
  gemm_kernel<<<dim3(5, 8), 256, 0, stream>>>(decb, 512, j_fwd_W + 512, 1024, j_fwd_b,
                                              dab, 1, 512, B_ * U1_, 512);

  // encoder: 3 BiLSTM layers
  bf16* xcur = xa;
  for (int lyr = 0; lyr < 3; ++lyr) {
    int K = (lyr == 0) ? 128 : 1024;
    bf16* xnext = (xcur == xa) ? xb : xa;
    for (int dd = 0; dd < 2; ++dd) {
      gemm_kernel<<<dim3(19, 32), 256, 0, stream>>>(
          xcur, 1024,
          enc_Wih + (size_t)(lyr * 2 + dd) * G4_ * 1024, 1024,
          enc_b + (size_t)(lyr * 2 + dd) * G4_,
          xg + (size_t)dd * B_ * T_ * G4_, 1, G4_, B_ * T_, K);
    }
    scan_kernel<<<dim3(NW_, 2), 256, 0, stream>>>(
        xg, enc_Whh + (size_t)lyr * 2 * G4_ * H_,
        inputs_length, 0, T_, 2, xnext, 1024, hbuf, bars);
    xcur = xnext;
  }
  gemm_kernel<<<dim3(19, 8), 256, 0, stream>>>(xcur, 1024, enc_proj_W, 1024, enc_proj_b,
                                               encb, 0, 512, B_ * T_, 1024);
  gemm_kernel<<<dim3(19, 8), 256, 0, stream>>>(encb, 512, j_fwd_W, 1024, (const float*)nullptr,
                                               eab, 1, 512, B_ * T_, 512);

  joint_kernel<<<dim3(NTILE_, 4, B_), 256, 0, stream>>>(eab, dab, j_proj_W, j_proj_b, targets,
                                                        blank, lab, jstats);
  finalize_kernel<<<(B_ * RPB_ + 255) / 256, 256, 0, stream>>>(jstats, blank, lab);
  loss_kernel<<<1, 256, 0, stream>>>(blank, lab, inputs_length, targets_length, (float*)d_out);
}

// Round 5
// 12026.141 us; speedup vs baseline: 1.3398x; 1.3398x over previous
//
#include <hip/hip_runtime.h>
#include <hip/hip_bf16.h>

#define B_ 4
#define T_ 300
#define U_ 64
#define U1_ 65
#define V_ 1024
#define H_ 512
#define G4_ 2048
#define NW_ 32
#define RPB_ (T_ * U1_)   // 19500 rows per batch in joint
#define NTILE_ 305        // ceil(19500/64)
#define RPAD_ 19520       // NTILE_*64

typedef __hip_bfloat16 bf16;
typedef __attribute__((ext_vector_type(8))) short short8;
typedef __attribute__((ext_vector_type(4))) float floatx4;

__device__ __forceinline__ float b2f(bf16 x) { return __bfloat162float(x); }
__device__ __forceinline__ bf16 f2b(float x) { return __float2bfloat16(x); }
__device__ __forceinline__ short bf16bits(float x) {
  bf16 h = __float2bfloat16(x);
  return *reinterpret_cast<short*>(&h);
}
__device__ __forceinline__ short8 pack8(float4 a, float4 b) {
  short8 p;
  p[0] = bf16bits(a.x); p[1] = bf16bits(a.y); p[2] = bf16bits(a.z); p[3] = bf16bits(a.w);
  p[4] = bf16bits(b.x); p[5] = bf16bits(b.y); p[6] = bf16bits(b.z); p[7] = bf16bits(b.w);
  return p;
}
__device__ __forceinline__ float sigm_(float x) { return 1.f / (1.f + __expf(-x)); }
__device__ __forceinline__ float tanh_(float x) { return 1.f - 2.f / (1.f + __expf(2.f * x)); }
__device__ __forceinline__ float lae_(float x, float y) {
  float m = fmaxf(x, y);
  float n = fminf(x, y);
  return m + __logf(1.f + __expf(n - m));
}

// ---------------- prep: pad layer-0 input (80 -> 128 cols of a 1024-stride buf), zero counters
__global__ void prep_kernel(const float* __restrict__ in, bf16* __restrict__ x0, int* __restrict__ bars) {
  int i = blockIdx.x * 256 + threadIdx.x;
  if (i < B_ * T_ * 128) {
    int k = i & 127;
    int row = i >> 7;
    float v = (k < 80) ? in[row * 80 + k] : 0.f;
    x0[(size_t)row * 1024 + k] = f2b(v);
  }
  if (blockIdx.x == 0 && threadIdx.x < 32) bars[threadIdx.x] = 0;
}

// ---------------- embedding gather (f32 table -> bf16)
__global__ void embed_kernel(const float* __restrict__ emb, const int* __restrict__ tgt,
                             bf16* __restrict__ demb) {
  int i = blockIdx.x * 256 + threadIdx.x;
  if (i >= B_ * U1_ * 512) return;
  int k = i & 511;
  int bu = i >> 9;
  int u = bu % U1_, b = bu / U1_;
  int id = (u == 0) ? 0 : tgt[b * U_ + u - 1];
  demb[i] = f2b(emb[(size_t)id * 512 + k]);
}

// ---------------- bf16-A x f32-W MFMA GEMM: C[M x (grid.y*64)] = A[M,K] @ W[N,K]^T + bias
__global__ __launch_bounds__(256) void gemm_kernel(
    const bf16* __restrict__ A, int lda,
    const float* __restrict__ W, int ldw,
    const float* __restrict__ bias,
    void* __restrict__ Cout, int out_f32, int ldc,
    int M, int K) {
  __shared__ __align__(16) bf16 As[64][72];
  __shared__ __align__(16) bf16 Bs[64][72];
  int m0 = blockIdx.x * 64, n0 = blockIdx.y * 64;
  int tid = threadIdx.x, w = tid >> 6, l = tid & 63;
  int l4 = l & 15, lq = l >> 4;
  floatx4 acc[4];
#pragma unroll
  for (int nt = 0; nt < 4; ++nt) acc[nt] = (floatx4){0.f, 0.f, 0.f, 0.f};
  for (int k0 = 0; k0 < K; k0 += 64) {
    __syncthreads();
#pragma unroll
    for (int q = 0; q < 2; ++q) {
      int cc = tid + q * 256;
      int r = cc >> 3, kc = (cc & 7) * 8;
      short8 va = {0, 0, 0, 0, 0, 0, 0, 0};
      int gm = m0 + r;
      if (gm < M) va = *(const short8*)(A + (size_t)gm * lda + k0 + kc);
      *(short8*)(&As[r][kc]) = va;
      const float* wp = W + (size_t)(n0 + r) * ldw + k0 + kc;
      float4 w0 = *(const float4*)(wp);
      float4 w1 = *(const float4*)(wp + 4);
      *(short8*)(&Bs[r][kc]) = pack8(w0, w1);
    }
    __syncthreads();
#pragma unroll
    for (int kk = 0; kk < 64; kk += 32) {
      short8 a = *(const short8*)(&As[w * 16 + l4][kk + lq * 8]);
#pragma unroll
      for (int nt = 0; nt < 4; ++nt) {
        short8 bb = *(const short8*)(&Bs[nt * 16 + l4][kk + lq * 8]);
        acc[nt] = __builtin_amdgcn_mfma_f32_16x16x32_bf16(a, bb, acc[nt], 0, 0, 0);
      }
    }
  }
#pragma unroll
  for (int nt = 0; nt < 4; ++nt) {
    int col = n0 + nt * 16 + l4;
    float bv = bias ? bias[col] : 0.f;
#pragma unroll
    for (int r = 0; r < 4; ++r) {
      int row = m0 + w * 16 + lq * 4 + r;
      if (row < M) {
        float v = acc[nt][r] + bv;
        if (out_f32) ((float*)Cout)[(size_t)row * ldc + col] = v;
        else ((bf16*)Cout)[(size_t)row * ldc + col] = f2b(v);
      }
    }
  }
}

// ---------------- persistent LSTM scan, 1-phase produce-counter sync.
// grid = (NW_, ndir). WG w owns h-dims [w*16, w*16+16) across all 4 gates.
// h double-buffered in global: h_buf[parity][dir][B][512]. cnt = 2 ints per dir.
__global__ __launch_bounds__(256, 1) void scan_kernel(
    const float* __restrict__ xg,      // [ndir][B][Tmax][2048] f32
    const float* __restrict__ whh,     // [ndir][2048][512] f32
    const int* __restrict__ len_raw, int len_add,
    int Tmax, int bwd_mask,
    bf16* __restrict__ out, int out_stride,
    float* __restrict__ h_buf,
    int* __restrict__ cnt) {
  int w = blockIdx.x, d = blockIdx.y;
  int tid = threadIdx.x;
  const float* xg_d = xg + (size_t)d * B_ * Tmax * G4_;
  const float* whh_d = whh + (size_t)d * G4_ * H_;
  int* c01 = cnt + d * 2;
  bool bwd = (bwd_mask >> d) & 1;

  int row = tid & 63;          // gate = row>>4, dim = row&15
  int ks = tid >> 6;           // k-slice 0..3 (128 each)
  int grow = (row >> 4) * H_ + w * 16 + (row & 15);

  float wreg[128];
  {
    const float* wp = whh_d + (size_t)grow * H_ + ks * 128;
#pragma unroll
    for (int j = 0; j < 128; ++j) wreg[j] = wp[j];
  }

  __shared__ __align__(16) float h_lds[4][512];
  __shared__ float partial[4][64][5];
  __shared__ float gates[64][5];
  __shared__ float c_lds[16][4];
  __shared__ int len_s[4];

  if (tid < 4) len_s[tid] = len_raw[tid] + len_add;
  if (tid < 64) c_lds[tid & 15][tid >> 4] = 0.f;
  __syncthreads();
  int smax = max(max(len_s[0], len_s[1]), max(len_s[2], len_s[3]));
  int rb = tid >> 6;

  for (int s = 0; s < smax; ++s) {
    float4* dst = (float4*)&h_lds[0][0];
    if (s == 0) {
      float4 z = {0.f, 0.f, 0.f, 0.f};
      dst[tid] = z;
      dst[tid + 256] = z;
    } else {
      int pc = (s - 1) & 1;
      int target = 32 * (((s - 1) >> 1) + 1);
      while (__hip_atomic_load(&c01[pc], __ATOMIC_RELAXED, __HIP_MEMORY_SCOPE_AGENT) < target)
        __builtin_amdgcn_s_sleep(1);
      __builtin_amdgcn_fence(__ATOMIC_ACQUIRE, "agent");
      const float4* src = (const float4*)(h_buf + (size_t)(pc * 2 + d) * B_ * H_);
      dst[tid] = src[tid];
      dst[tid + 256] = src[tid + 256];
    }
    // prefetch xg value used in gates phase (hidden behind matvec)
    bool ract = s < len_s[rb];
    int rt = bwd ? (len_s[rb] - 1 - s) : s;
    if (!ract) rt = 0;
    float xv = xg_d[((size_t)rb * Tmax + rt) * G4_ + grow];
    __syncthreads();
    float a0 = 0.f, a1 = 0.f, a2 = 0.f, a3 = 0.f;
    {
      int kb = ks * 128;
#pragma unroll
      for (int j = 0; j < 128; ++j) {
        float wv = wreg[j];
        a0 = __builtin_fmaf(wv, h_lds[0][kb + j], a0);
        a1 = __builtin_fmaf(wv, h_lds[1][kb + j], a1);
        a2 = __builtin_fmaf(wv, h_lds[2][kb + j], a2);
        a3 = __builtin_fmaf(wv, h_lds[3][kb + j], a3);
      }
    }
    partial[ks][row][0] = a0;
    partial[ks][row][1] = a1;
    partial[ks][row][2] = a2;
    partial[ks][row][3] = a3;
    __syncthreads();
    gates[row][rb] = partial[0][row][rb] + partial[1][row][rb] +
                     partial[2][row][rb] + partial[3][row][rb] + xv;
    __syncthreads();
    if (tid < 64) {  // writers = wave 0 only
      int dim = tid & 15, bb = tid >> 4;
      if (s < len_s[bb]) {
        float gi = gates[dim][bb];
        float gf = gates[16 + dim][bb];
        float gg = gates[32 + dim][bb];
        float go = gates[48 + dim][bb];
        float c = c_lds[dim][bb];
        c = sigm_(gf) * c + sigm_(gi) * tanh_(gg);
        float h = sigm_(go) * tanh_(c);
        c_lds[dim][bb] = c;
        int t = bwd ? (len_s[bb] - 1 - s) : s;
        h_buf[(size_t)((s & 1) * 2 + d) * B_ * H_ + (size_t)bb * H_ + w * 16 + dim] = h;
        out[((size_t)bb * Tmax + t) * out_stride + d * H_ + w * 16 + dim] = f2b(h);
      }
    }
    if ((tid >> 6) == 0) {  // whole wave 0: drain its stores, publish
      __builtin_amdgcn_fence(__ATOMIC_RELEASE, "agent");
      if (tid == 0 && s + 1 < smax)
        __hip_atomic_fetch_add(&c01[s & 1], 1, __ATOMIC_RELAXED, __HIP_MEMORY_SCOPE_AGENT);
    }
  }
}

// ---------------- joint (<=48KB LDS): block = 64 rows x 256 cols, K=512.
__global__ __launch_bounds__(256) void joint_kernel(
    const float* __restrict__ ea, const float* __restrict__ da,
    const float* __restrict__ Wp, const float* __restrict__ pb,
    const int* __restrict__ targets,
    float* __restrict__ blankraw, float* __restrict__ labraw,
    float* __restrict__ jstats) {
  __shared__ __align__(16) bf16 As[64][72];
  __shared__ __align__(16) bf16 Bs[256][72];
  __shared__ float bias_s[256];
  __shared__ int tgt_s[64];
  __shared__ float pstat[64][2][2];

  int tid = threadIdx.x;
  int tile = blockIdx.x, cb = blockIdx.y, b = blockIdx.z;
  int r0 = tile * 64;

  bias_s[tid & 255] = pb[cb * 256 + (tid & 255)];
  if (tid < 64) {
    int r = r0 + tid;
    int u = r % U1_;
    tgt_s[tid] = (r < RPB_ && u < U_) ? targets[b * U_ + u] : -1;
  }
  int si = tid >> 2;
  int sseg = (tid & 3) * 16;
  int sr = r0 + si;
  bool svalid = sr < RPB_;
  int st = svalid ? sr / U1_ : 0;
  int su = svalid ? sr % U1_ : 0;
  const float* ep = ea + ((size_t)(b * T_ + st)) * 512 + sseg;
  const float* dp = da + ((size_t)(b * U1_ + su)) * 512 + sseg;

  int wid = tid >> 6, l = tid & 63;
  int wm = wid >> 1, wn = wid & 1;
  int l4 = l & 15, lq = l >> 4;

  floatx4 acc[2][8];
#pragma unroll
  for (int ms = 0; ms < 2; ++ms)
#pragma unroll
    for (int nt = 0; nt < 8; ++nt) acc[ms][nt] = (floatx4){0.f, 0.f, 0.f, 0.f};

  for (int k0 = 0; k0 < 512; k0 += 64) {
    __syncthreads();
    {
      const float* e = ep + k0;
      const float* d = dp + k0;
#pragma unroll
      for (int h = 0; h < 2; ++h) {
        float4 e0 = *(const float4*)(e + h * 8);
        float4 e1 = *(const float4*)(e + h * 8 + 4);
        float4 d0 = *(const float4*)(d + h * 8);
        float4 d1 = *(const float4*)(d + h * 8 + 4);
        short8 pk = {0, 0, 0, 0, 0, 0, 0, 0};
        if (svalid) {
          pk[0] = bf16bits(tanh_(e0.x + d0.x));
          pk[1] = bf16bits(tanh_(e0.y + d0.y));
          pk[2] = bf16bits(tanh_(e0.z + d0.z));
          pk[3] = bf16bits(tanh_(e0.w + d0.w));
          pk[4] = bf16bits(tanh_(e1.x + d1.x));
          pk[5] = bf16bits(tanh_(e1.y + d1.y));
          pk[6] = bf16bits(tanh_(e1.z + d1.z));
          pk[7] = bf16bits(tanh_(e1.w + d1.w));
        }
        *(short8*)(&As[si][sseg + h * 8]) = pk;
      }
    }
#pragma unroll
    for (int q = 0; q < 8; ++q) {
      int cc = tid + q * 256;
      int r = cc >> 3, kc = (cc & 7) * 8;
      const float* wp = Wp + (size_t)(cb * 256 + r) * 512 + k0 + kc;
      float4 w0 = *(const float4*)(wp);
      float4 w1 = *(const float4*)(wp + 4);
      *(short8*)(&Bs[r][kc]) = pack8(w0, w1);
    }
    __syncthreads();
#pragma unroll
    for (int kk = 0; kk < 64; kk += 32) {
      short8 af[2], bf8[8];
#pragma unroll
      for (int ms = 0; ms < 2; ++ms)
        af[ms] = *(const short8*)(&As[wm * 32 + ms * 16 + l4][kk + lq * 8]);
#pragma unroll
      for (int nt = 0; nt < 8; ++nt)
        bf8[nt] = *(const short8*)(&Bs[wn * 128 + nt * 16 + l4][kk + lq * 8]);
#pragma unroll
      for (int ms = 0; ms < 2; ++ms)
#pragma unroll
        for (int nt = 0; nt < 8; ++nt)
          acc[ms][nt] = __builtin_amdgcn_mfma_f32_16x16x32_bf16(af[ms], bf8[nt], acc[ms][nt], 0, 0, 0);
    }
  }
#pragma unroll
  for (int ms = 0; ms < 2; ++ms) {
#pragma unroll
    for (int r = 0; r < 4; ++r) {
      int i = wm * 32 + ms * 16 + lq * 4 + r;
      int grow = r0 + i;
      bool valid = grow < RPB_;
      int tg = tgt_s[i];
      float v[8];
      float mx = -1e30f;
#pragma unroll
      for (int nt = 0; nt < 8; ++nt) {
        int colc = wn * 128 + nt * 16 + l4;
        float x = acc[ms][nt][r] + bias_s[colc];
        v[nt] = x;
        mx = fmaxf(mx, x);
        int gcol = cb * 256 + colc;
        if (valid) {
          if (gcol == 0) blankraw[(size_t)b * RPB_ + grow] = x;
          if (gcol == tg) labraw[(size_t)b * RPB_ + grow] = x;
        }
      }
#pragma unroll
      for (int dd = 1; dd < 16; dd <<= 1) mx = fmaxf(mx, __shfl_xor(mx, dd, 64));
      float se = 0.f;
#pragma unroll
      for (int nt = 0; nt < 8; ++nt) se += __expf(v[nt] - mx);
#pragma unroll
      for (int dd = 1; dd < 16; dd <<= 1) se += __shfl_xor(se, dd, 64);
      if (l4 == 0) { pstat[i][wn][0] = mx; pstat[i][wn][1] = se; }
    }
  }
  __syncthreads();
  if (tid < 64) {
    float ma = pstat[tid][0][0], sa = pstat[tid][0][1];
    float mb = pstat[tid][1][0], sb = pstat[tid][1][1];
    float mc = fmaxf(ma, mb);
    float sc = sa * __expf(ma - mc) + sb * __expf(mb - mc);
    size_t o = (((size_t)b * RPAD_ + r0 + tid) * 4 + cb) * 2;
    jstats[o] = mc;
    jstats[o + 1] = sc;
  }
}

// ---------------- finalize: merge 4 col-block stats -> lse; convert raw logits to log-probs
__global__ void finalize_kernel(const float* __restrict__ jstats,
                                float* __restrict__ blank, float* __restrict__ lab) {
  int g = blockIdx.x * 256 + threadIdx.x;
  if (g >= B_ * RPB_) return;
  int b = g / RPB_, r = g % RPB_;
  const float* st = jstats + ((size_t)b * RPAD_ + r) * 8;
  float M = fmaxf(fmaxf(st[0], st[2]), fmaxf(st[4], st[6]));
  float s = st[1] * __expf(st[0] - M) + st[3] * __expf(st[2] - M) +
            st[5] * __expf(st[4] - M) + st[7] * __expf(st[6] - M);
  float lse = M + __logf(s);
  blank[g] -= lse;
  if ((r % U1_) < U_) lab[g] -= lse;
}

// ---------------- RNNT loss (OUTPUT IS FLOAT32)
__global__ void loss_kernel(const float* __restrict__ blank, const float* __restrict__ lab,
                            const int* __restrict__ Tl, const int* __restrict__ Ul,
                            float* __restrict__ outp) {
  int b = threadIdx.x >> 6;
  int l = threadIdx.x & 63;
  int TL = Tl[b], UL = Ul[b];
  float alpha_l = 0.f, alpha0 = 0.f;
  for (int t = 0; t < TL; ++t) {
    float a_u0, a_l1;
    if (t == 0) { a_u0 = 0.f; a_l1 = -1e30f; }
    else {
      const float* bl = blank + ((size_t)b * T_ + (t - 1)) * U1_;
      a_u0 = alpha0 + bl[0];
      a_l1 = alpha_l + bl[l + 1];
    }
    const float* lb = lab + ((size_t)b * T_ + t) * U1_;
    float C = lb[l];
#pragma unroll
    for (int dd = 1; dd < 64; dd <<= 1) {
      float o = __shfl_up(C, dd, 64);
      if (l >= dd) C += o;
    }
    float S = a_l1 - C;
#pragma unroll
    for (int dd = 1; dd < 64; dd <<= 1) {
      float o = __shfl_up(S, dd, 64);
      if (l >= dd) S = lae_(S, o);
    }
    alpha_l = C + lae_(a_u0, S);
    alpha0 = a_u0;
  }
  float av = (UL == 0) ? alpha0 : __shfl(alpha_l, UL - 1, 64);
  float ll = av + blank[((size_t)b * T_ + (TL - 1)) * U1_ + UL];
  __shared__ float lls[4];
  if (l == 0) lls[b] = ll;
  __syncthreads();
  if (threadIdx.x == 0) outp[0] = -0.25f * (lls[0] + lls[1] + lls[2] + lls[3]);
}

// ---------------- workspace layout (bytes)
static constexpr size_t OFF_XG = 0;                                        // f32 [2][4][300][2048]
static constexpr size_t OFF_XA = OFF_XG + (size_t)2 * B_ * T_ * G4_ * 4;   // bf16 [4][300][1024]
static constexpr size_t OFF_XB = OFF_XA + (size_t)B_ * T_ * 1024 * 2;
static constexpr size_t OFF_ENC = OFF_XB + (size_t)B_ * T_ * 1024 * 2;     // bf16 [4][300][512]
static constexpr size_t OFF_EA = OFF_ENC + (size_t)B_ * T_ * 512 * 2;      // f32
static constexpr size_t OFF_DEMB = OFF_EA + (size_t)B_ * T_ * 512 * 4;     // bf16
static constexpr size_t OFF_DXG = OFF_DEMB + (size_t)B_ * U1_ * 512 * 2;   // f32
static constexpr size_t OFF_DH = OFF_DXG + (size_t)B_ * U1_ * G4_ * 4;     // bf16
static constexpr size_t OFF_DEC = OFF_DH + (size_t)B_ * U1_ * 512 * 2;     // bf16
static constexpr size_t OFF_DA = OFF_DEC + (size_t)B_ * U1_ * 512 * 2;     // f32
static constexpr size_t OFF_BL = OFF_DA + (size_t)B_ * U1_ * 512 * 4;      // f32 [4][300][65]
static constexpr size_t OFF_LAB = OFF_BL + (size_t)B_ * T_ * U1_ * 4;
static constexpr size_t OFF_HBUF = OFF_LAB + (size_t)B_ * T_ * U1_ * 4;    // f32 [2][2][4][512]
static constexpr size_t OFF_BARS = OFF_HBUF + (size_t)2 * 2 * B_ * H_ * 4; // 32 ints
static constexpr size_t OFF_JST = OFF_BARS + 128;                          // f32 [4][19520][4][2]

extern "C" void kernel_launch(void* const* d_in, const int* in_sizes, int n_in,
                              void* d_out, int out_size, void* d_ws, size_t ws_size,
                              hipStream_t stream) {
  (void)in_sizes; (void)n_in; (void)out_size; (void)ws_size;
  const float* inputs = (const float*)d_in[0];
  const int* inputs_length = (const int*)d_in[1];
  const int* targets = (const int*)d_in[2];
  const int* targets_length = (const int*)d_in[3];
  const float* enc_Wih = (const float*)d_in[4];
  const float* enc_Whh = (const float*)d_in[5];
  const float* enc_b = (const float*)d_in[6];
  const float* enc_proj_W = (const float*)d_in[7];
  const float* enc_proj_b = (const float*)d_in[8];
  const float* dec_emb = (const float*)d_in[9];
  const float* dec_Wih = (const float*)d_in[10];
  const float* dec_Whh = (const float*)d_in[11];
  const float* dec_b = (const float*)d_in[12];
  const float* dec_proj_W = (const float*)d_in[13];
  const float* dec_proj_b = (const float*)d_in[14];
  const float* j_fwd_W = (const float*)d_in[15];
  const float* j_fwd_b = (const float*)d_in[16];
  const float* j_proj_W = (const float*)d_in[17];
  const float* j_proj_b = (const float*)d_in[18];

  char* ws = (char*)d_ws;
  float* xg = (float*)(ws + OFF_XG);
  bf16* xa = (bf16*)(ws + OFF_XA);
  bf16* xb = (bf16*)(ws + OFF_XB);
  bf16* encb = (bf16*)(ws + OFF_ENC);
  float* eab = (float*)(ws + OFF_EA);
  bf16* demb = (bf16*)(ws + OFF_DEMB);
  float* dxg = (float*)(ws + OFF_DXG);
  bf16* dh = (bf16*)(ws + OFF_DH);
  bf16* decb = (bf16*)(ws + OFF_DEC);
  float* dab = (float*)(ws + OFF_DA);
  float* blank = (float*)(ws + OFF_BL);
  float* lab = (float*)(ws + OFF_LAB);
  float* hbuf = (float*)(ws + OFF_HBUF);
  int* bars = (int*)(ws + OFF_BARS);
  float* jstats = (float*)(ws + OFF_JST);

  prep_kernel<<<600, 256, 0, stream>>>(inputs, xa, bars);
  embed_kernel<<<520, 256, 0, stream>>>(dec_emb, targets, demb);

  // decoder chain (counters: ints 0..1)
  gemm_kernel<<<dim3(5, 32), 256, 0, stream>>>(demb, 512, dec_Wih, 512, dec_b,
                                               dxg, 1, G4_, B_ * U1_, 512);
  scan_kernel<<<dim3(NW_, 1), 256, 0, stream>>>(dxg, dec_Whh, targets_length, 1, U1_, 0,
                                                dh, 512, hbuf, bars);
  gemm_kernel<<<dim3(5, 8), 256, 0, stream>>>(dh, 512, dec_proj_W, 512, dec_proj_b,
                                              decb, 0, 512, B_ * U1_, 512);
  gemm_kernel<<<dim3(5, 8), 256, 0, stream>>>(decb, 512, j_fwd_W + 512, 1024, j_fwd_b,
                                              dab, 1, 512, B_ * U1_, 512);

  // encoder: 3 BiLSTM layers (layer l counters: ints 4+4l .. 7+4l)
  bf16* xcur = xa;
  for (int lyr = 0; lyr < 3; ++lyr) {
    int K = (lyr == 0) ? 128 : 1024;
    bf16* xnext = (xcur == xa) ? xb : xa;
    for (int dd = 0; dd < 2; ++dd) {
      gemm_kernel<<<dim3(19, 32), 256, 0, stream>>>(
          xcur, 1024,
          enc_Wih + (size_t)(lyr * 2 + dd) * G4_ * 1024, 1024,
          enc_b + (size_t)(lyr * 2 + dd) * G4_,
          xg + (size_t)dd * B_ * T_ * G4_, 1, G4_, B_ * T_, K);
    }
    scan_kernel<<<dim3(NW_, 2), 256, 0, stream>>>(
        xg, enc_Whh + (size_t)lyr * 2 * G4_ * H_,
        inputs_length, 0, T_, 2, xnext, 1024, hbuf, bars + 4 + lyr * 4);
    xcur = xnext;
  }
  gemm_kernel<<<dim3(19, 8), 256, 0, stream>>>(xcur, 1024, enc_proj_W, 1024, enc_proj_b,
                                               encb, 0, 512, B_ * T_, 1024);
  gemm_kernel<<<dim3(19, 8), 256, 0, stream>>>(encb, 512, j_fwd_W, 1024, (const float*)nullptr,
                                               eab, 1, 512, B_ * T_, 512);

  joint_kernel<<<dim3(NTILE_, 4, B_), 256, 0, stream>>>(eab, dab, j_proj_W, j_proj_b, targets,
                                                        blank, lab, jstats);
  finalize_kernel<<<(B_ * RPB_ + 255) / 256, 256, 0, stream>>>(jstats, blank, lab);
  loss_kernel<<<1, 256, 0, stream>>>(blank, lab, inputs_length, targets_length, (float*)d_out);
}

// Round 6
// 7356.451 us; speedup vs baseline: 2.1903x; 1.6348x over previous
//
#include <hip/hip_runtime.h>
#include <hip/hip_bf16.h>

#define B_ 4
#define T_ 300
#define U_ 64
#define U1_ 65
#define V_ 1024
#define H_ 512
#define G4_ 2048
#define NW_ 32
#define RPB_ (T_ * U1_)   // 19500 rows per batch in joint
#define NTILE_ 305        // ceil(19500/64)
#define RPAD_ 19520       // NTILE_*64

typedef __hip_bfloat16 bf16;
typedef __attribute__((ext_vector_type(8))) short short8;
typedef __attribute__((ext_vector_type(4))) float floatx4;

__device__ __forceinline__ float b2f(bf16 x) { return __bfloat162float(x); }
__device__ __forceinline__ bf16 f2b(float x) { return __float2bfloat16(x); }
__device__ __forceinline__ short bf16bits(float x) {
  bf16 h = __float2bfloat16(x);
  return *reinterpret_cast<short*>(&h);
}
__device__ __forceinline__ short8 pack8(float4 a, float4 b) {
  short8 p;
  p[0] = bf16bits(a.x); p[1] = bf16bits(a.y); p[2] = bf16bits(a.z); p[3] = bf16bits(a.w);
  p[4] = bf16bits(b.x); p[5] = bf16bits(b.y); p[6] = bf16bits(b.z); p[7] = bf16bits(b.w);
  return p;
}
__device__ __forceinline__ float sigm_(float x) { return 1.f / (1.f + __expf(-x)); }
__device__ __forceinline__ float tanh_(float x) { return 1.f - 2.f / (1.f + __expf(2.f * x)); }
__device__ __forceinline__ float lae_(float x, float y) {
  float m = fmaxf(x, y);
  float n = fminf(x, y);
  return m + __logf(1.f + __expf(n - m));
}

// ---------------- prep: pad layer-0 input (80 -> 128 cols of a 1024-stride buf), zero flags
__global__ void prep_kernel(const float* __restrict__ in, bf16* __restrict__ x0, int* __restrict__ bars) {
  int i = blockIdx.x * 256 + threadIdx.x;
  if (i < B_ * T_ * 128) {
    int k = i & 127;
    int row = i >> 7;
    float v = (k < 80) ? in[row * 80 + k] : 0.f;
    x0[(size_t)row * 1024 + k] = f2b(v);
  }
  if (i < 4096) bars[i] = 0;
}

// ---------------- embedding gather (f32 table -> bf16)
__global__ void embed_kernel(const float* __restrict__ emb, const int* __restrict__ tgt,
                             bf16* __restrict__ demb) {
  int i = blockIdx.x * 256 + threadIdx.x;
  if (i >= B_ * U1_ * 512) return;
  int k = i & 511;
  int bu = i >> 9;
  int u = bu % U1_, b = bu / U1_;
  int id = (u == 0) ? 0 : tgt[b * U_ + u - 1];
  demb[i] = f2b(emb[(size_t)id * 512 + k]);
}

// ---------------- bf16-A x f32-W MFMA GEMM: C[M x (grid.y*64)] = A[M,K] @ W[N,K]^T + bias
__global__ __launch_bounds__(256) void gemm_kernel(
    const bf16* __restrict__ A, int lda,
    const float* __restrict__ W, int ldw,
    const float* __restrict__ bias,
    void* __restrict__ Cout, int out_f32, int ldc,
    int M, int K) {
  __shared__ __align__(16) bf16 As[64][72];
  __shared__ __align__(16) bf16 Bs[64][72];
  int m0 = blockIdx.x * 64, n0 = blockIdx.y * 64;
  int tid = threadIdx.x, w = tid >> 6, l = tid & 63;
  int l4 = l & 15, lq = l >> 4;
  floatx4 acc[4];
#pragma unroll
  for (int nt = 0; nt < 4; ++nt) acc[nt] = (floatx4){0.f, 0.f, 0.f, 0.f};
  for (int k0 = 0; k0 < K; k0 += 64) {
    __syncthreads();
#pragma unroll
    for (int q = 0; q < 2; ++q) {
      int cc = tid + q * 256;
      int r = cc >> 3, kc = (cc & 7) * 8;
      short8 va = {0, 0, 0, 0, 0, 0, 0, 0};
      int gm = m0 + r;
      if (gm < M) va = *(const short8*)(A + (size_t)gm * lda + k0 + kc);
      *(short8*)(&As[r][kc]) = va;
      const float* wp = W + (size_t)(n0 + r) * ldw + k0 + kc;
      float4 w0 = *(const float4*)(wp);
      float4 w1 = *(const float4*)(wp + 4);
      *(short8*)(&Bs[r][kc]) = pack8(w0, w1);
    }
    __syncthreads();
#pragma unroll
    for (int kk = 0; kk < 64; kk += 32) {
      short8 a = *(const short8*)(&As[w * 16 + l4][kk + lq * 8]);
#pragma unroll
      for (int nt = 0; nt < 4; ++nt) {
        short8 bb = *(const short8*)(&Bs[nt * 16 + l4][kk + lq * 8]);
        acc[nt] = __builtin_amdgcn_mfma_f32_16x16x32_bf16(a, bb, acc[nt], 0, 0, 0);
      }
    }
  }
#pragma unroll
  for (int nt = 0; nt < 4; ++nt) {
    int col = n0 + nt * 16 + l4;
    float bv = bias ? bias[col] : 0.f;
#pragma unroll
    for (int r = 0; r < 4; ++r) {
      int row = m0 + w * 16 + lq * 4 + r;
      if (row < M) {
        float v = acc[nt][r] + bv;
        if (out_f32) ((float*)Cout)[(size_t)row * ldc + col] = v;
        else ((bf16*)Cout)[(size_t)row * ldc + col] = f2b(v);
      }
    }
  }
}

// ---------------- persistent LSTM scan, fence-free LLC protocol.
// grid = (NW_, ndir). WG w owns h-dims [w*16,w*16+16) x 4 gates.
// h lives at the coherence point: relaxed agent-scope atomic stores/loads only.
// Per-WG flag (64B apart) = number of completed steps; no RMW, no fences.
__global__ __launch_bounds__(256, 1) void scan_kernel(
    const float* __restrict__ xg,      // [ndir][B][Tmax][2048] f32
    const float* __restrict__ whh,     // [ndir][2048][512] f32
    const int* __restrict__ len_raw, int len_add,
    int Tmax, int bwd_mask,
    bf16* __restrict__ out, int out_stride,
    float* __restrict__ h_buf,         // [2][2][B][512] f32
    int* __restrict__ flags) {         // per dir: flags + d*512; WG w at [w*16]
  int w = blockIdx.x, d = blockIdx.y;
  int tid = threadIdx.x;
  const float* xg_d = xg + (size_t)d * B_ * Tmax * G4_;
  const float* whh_d = whh + (size_t)d * G4_ * H_;
  int* flg = flags + d * 512;
  bool bwd = (bwd_mask >> d) & 1;

  int row = tid & 63;          // gate = row>>4, dim = row&15
  int ks = tid >> 6;           // k-slice 0..3 (128 each)
  int lane = tid & 63;
  int grow = (row >> 4) * H_ + w * 16 + (row & 15);

  float wreg[128];
  {
    const float* wp = whh_d + (size_t)grow * H_ + ks * 128;
#pragma unroll
    for (int j = 0; j < 128; ++j) wreg[j] = wp[j];
  }

  __shared__ __align__(16) float h_lds[4][512];
  __shared__ float partial[4][64][5];
  __shared__ float gates[64][5];
  __shared__ float c_lds[16][4];
  __shared__ int len_s[4];

  if (tid < 4) len_s[tid] = len_raw[tid] + len_add;
  if (tid < 64) c_lds[tid & 15][tid >> 4] = 0.f;
  __syncthreads();
  int smax = max(max(len_s[0], len_s[1]), max(len_s[2], len_s[3]));
  int rb = tid >> 6;

  for (int s = 0; s < smax; ++s) {
    // prefetch xg value used in gates phase (independent of h)
    bool ract = s < len_s[rb];
    int rt = bwd ? (len_s[rb] - 1 - s) : s;
    if (!ract) rt = 0;
    float xv = xg_d[((size_t)rb * Tmax + rt) * G4_ + grow];

    if (s == 0) {
      float4* dst = (float4*)&h_lds[0][0];
      float4 z = {0.f, 0.f, 0.f, 0.f};
      dst[tid] = z;
      dst[tid + 256] = z;
    } else {
      // wait: every WG has completed step s-1 (h(s-1) at LLC)
      for (;;) {
        int v = (lane < NW_)
                    ? __hip_atomic_load(&flg[lane * 16], __ATOMIC_RELAXED, __HIP_MEMORY_SCOPE_AGENT)
                    : s;
        if (__all(v >= s)) break;
        __builtin_amdgcn_s_sleep(1);
      }
      // load h(s-1) from LLC -> LDS (8 floats per thread)
      const float* src = h_buf + (size_t)(((s - 1) & 1) * 2 + d) * B_ * H_;
      float* hl = &h_lds[0][0];
#pragma unroll
      for (int q = 0; q < 8; ++q) {
        int i = tid + q * 256;
        hl[i] = __hip_atomic_load(src + i, __ATOMIC_RELAXED, __HIP_MEMORY_SCOPE_AGENT);
      }
    }
    __syncthreads();
    // matvec: 4 batches, b128 LDS broadcasts
    float a0 = 0.f, a1 = 0.f, a2 = 0.f, a3 = 0.f;
    {
      int kb = ks * 128;
      const float4* hb0 = (const float4*)&h_lds[0][kb];
      const float4* hb1 = (const float4*)&h_lds[1][kb];
      const float4* hb2 = (const float4*)&h_lds[2][kb];
      const float4* hb3 = (const float4*)&h_lds[3][kb];
#pragma unroll
      for (int j = 0; j < 32; ++j) {
        float w0 = wreg[4 * j], w1 = wreg[4 * j + 1], w2 = wreg[4 * j + 2], w3 = wreg[4 * j + 3];
        float4 x0 = hb0[j], x1 = hb1[j], x2 = hb2[j], x3 = hb3[j];
        a0 += w0 * x0.x + w1 * x0.y + w2 * x0.z + w3 * x0.w;
        a1 += w0 * x1.x + w1 * x1.y + w2 * x1.z + w3 * x1.w;
        a2 += w0 * x2.x + w1 * x2.y + w2 * x2.z + w3 * x2.w;
        a3 += w0 * x3.x + w1 * x3.y + w2 * x3.z + w3 * x3.w;
      }
    }
    partial[ks][row][0] = a0;
    partial[ks][row][1] = a1;
    partial[ks][row][2] = a2;
    partial[ks][row][3] = a3;
    __syncthreads();
    gates[row][rb] = partial[0][row][rb] + partial[1][row][rb] +
                     partial[2][row][rb] + partial[3][row][rb] + xv;
    __syncthreads();
    float hval = 0.f;
    int tdim = tid & 15, tbb = tid >> 4;
    bool wactive = (tid < 64) && (s < len_s[tbb]);
    if (wactive) {
      float gi = gates[tdim][tbb];
      float gf = gates[16 + tdim][tbb];
      float gg = gates[32 + tdim][tbb];
      float go = gates[48 + tdim][tbb];
      float c = c_lds[tdim][tbb];
      c = sigm_(gf) * c + sigm_(gi) * tanh_(gg);
      hval = sigm_(go) * tanh_(c);
      c_lds[tdim][tbb] = c;
      // h -> LLC (coherent, no fence needed)
      __hip_atomic_store(
          h_buf + (size_t)((s & 1) * 2 + d) * B_ * H_ + (size_t)tbb * H_ + w * 16 + tdim,
          hval, __ATOMIC_RELAXED, __HIP_MEMORY_SCOPE_AGENT);
    }
    if (tid < 64) {
      __builtin_amdgcn_s_waitcnt(0);  // drain wave-0 stores (acked at LLC)
      if (tid == 0)
        __hip_atomic_store(&flg[w * 16], s + 1, __ATOMIC_RELAXED, __HIP_MEMORY_SCOPE_AGENT);
      // activation store off the critical path
      if (wactive) {
        int t = bwd ? (len_s[tbb] - 1 - s) : s;
        out[((size_t)tbb * Tmax + t) * out_stride + d * H_ + w * 16 + tdim] = f2b(hval);
      }
    }
  }
}

// ---------------- joint (<=48KB LDS): block = 64 rows x 256 cols, K=512.
__global__ __launch_bounds__(256) void joint_kernel(
    const float* __restrict__ ea, const float* __restrict__ da,
    const float* __restrict__ Wp, const float* __restrict__ pb,
    const int* __restrict__ targets,
    float* __restrict__ blankraw, float* __restrict__ labraw,
    float* __restrict__ jstats) {
  __shared__ __align__(16) bf16 As[64][72];
  __shared__ __align__(16) bf16 Bs[256][72];
  __shared__ float bias_s[256];
  __shared__ int tgt_s[64];
  __shared__ float pstat[64][2][2];

  int tid = threadIdx.x;
  int tile = blockIdx.x, cb = blockIdx.y, b = blockIdx.z;
  int r0 = tile * 64;

  bias_s[tid & 255] = pb[cb * 256 + (tid & 255)];
  if (tid < 64) {
    int r = r0 + tid;
    int u = r % U1_;
    tgt_s[tid] = (r < RPB_ && u < U_) ? targets[b * U_ + u] : -1;
  }
  int si = tid >> 2;
  int sseg = (tid & 3) * 16;
  int sr = r0 + si;
  bool svalid = sr < RPB_;
  int st = svalid ? sr / U1_ : 0;
  int su = svalid ? sr % U1_ : 0;
  const float* ep = ea + ((size_t)(b * T_ + st)) * 512 + sseg;
  const float* dp = da + ((size_t)(b * U1_ + su)) * 512 + sseg;

  int wid = tid >> 6, l = tid & 63;
  int wm = wid >> 1, wn = wid & 1;
  int l4 = l & 15, lq = l >> 4;

  floatx4 acc[2][8];
#pragma unroll
  for (int ms = 0; ms < 2; ++ms)
#pragma unroll
    for (int nt = 0; nt < 8; ++nt) acc[ms][nt] = (floatx4){0.f, 0.f, 0.f, 0.f};

  for (int k0 = 0; k0 < 512; k0 += 64) {
    __syncthreads();
    {
      const float* e = ep + k0;
      const float* d = dp + k0;
#pragma unroll
      for (int h = 0; h < 2; ++h) {
        float4 e0 = *(const float4*)(e + h * 8);
        float4 e1 = *(const float4*)(e + h * 8 + 4);
        float4 d0 = *(const float4*)(d + h * 8);
        float4 d1 = *(const float4*)(d + h * 8 + 4);
        short8 pk = {0, 0, 0, 0, 0, 0, 0, 0};
        if (svalid) {
          pk[0] = bf16bits(tanh_(e0.x + d0.x));
          pk[1] = bf16bits(tanh_(e0.y + d0.y));
          pk[2] = bf16bits(tanh_(e0.z + d0.z));
          pk[3] = bf16bits(tanh_(e0.w + d0.w));
          pk[4] = bf16bits(tanh_(e1.x + d1.x));
          pk[5] = bf16bits(tanh_(e1.y + d1.y));
          pk[6] = bf16bits(tanh_(e1.z + d1.z));
          pk[7] = bf16bits(tanh_(e1.w + d1.w));
        }
        *(short8*)(&As[si][sseg + h * 8]) = pk;
      }
    }
#pragma unroll
    for (int q = 0; q < 8; ++q) {
      int cc = tid + q * 256;
      int r = cc >> 3, kc = (cc & 7) * 8;
      const float* wp = Wp + (size_t)(cb * 256 + r) * 512 + k0 + kc;
      float4 w0 = *(const float4*)(wp);
      float4 w1 = *(const float4*)(wp + 4);
      *(short8*)(&Bs[r][kc]) = pack8(w0, w1);
    }
    __syncthreads();
#pragma unroll
    for (int kk = 0; kk < 64; kk += 32) {
      short8 af[2], bf8[8];
#pragma unroll
      for (int ms = 0; ms < 2; ++ms)
        af[ms] = *(const short8*)(&As[wm * 32 + ms * 16 + l4][kk + lq * 8]);
#pragma unroll
      for (int nt = 0; nt < 8; ++nt)
        bf8[nt] = *(const short8*)(&Bs[wn * 128 + nt * 16 + l4][kk + lq * 8]);
#pragma unroll
      for (int ms = 0; ms < 2; ++ms)
#pragma unroll
        for (int nt = 0; nt < 8; ++nt)
          acc[ms][nt] = __builtin_amdgcn_mfma_f32_16x16x32_bf16(af[ms], bf8[nt], acc[ms][nt], 0, 0, 0);
    }
  }
#pragma unroll
  for (int ms = 0; ms < 2; ++ms) {
#pragma unroll
    for (int r = 0; r < 4; ++r) {
      int i = wm * 32 + ms * 16 + lq * 4 + r;
      int grow = r0 + i;
      bool valid = grow < RPB_;
      int tg = tgt_s[i];
      float v[8];
      float mx = -1e30f;
#pragma unroll
      for (int nt = 0; nt < 8; ++nt) {
        int colc = wn * 128 + nt * 16 + l4;
        float x = acc[ms][nt][r] + bias_s[colc];
        v[nt] = x;
        mx = fmaxf(mx, x);
        int gcol = cb * 256 + colc;
        if (valid) {
          if (gcol == 0) blankraw[(size_t)b * RPB_ + grow] = x;
          if (gcol == tg) labraw[(size_t)b * RPB_ + grow] = x;
        }
      }
#pragma unroll
      for (int dd = 1; dd < 16; dd <<= 1) mx = fmaxf(mx, __shfl_xor(mx, dd, 64));
      float se = 0.f;
#pragma unroll
      for (int nt = 0; nt < 8; ++nt) se += __expf(v[nt] - mx);
#pragma unroll
      for (int dd = 1; dd < 16; dd <<= 1) se += __shfl_xor(se, dd, 64);
      if (l4 == 0) { pstat[i][wn][0] = mx; pstat[i][wn][1] = se; }
    }
  }
  __syncthreads();
  if (tid < 64) {
    float ma = pstat[tid][0][0], sa = pstat[tid][0][1];
    float mb = pstat[tid][1][0], sb = pstat[tid][1][1];
    float mc = fmaxf(ma, mb);
    float sc = sa * __expf(ma - mc) + sb * __expf(mb - mc);
    size_t o = (((size_t)b * RPAD_ + r0 + tid) * 4 + cb) * 2;
    jstats[o] = mc;
    jstats[o + 1] = sc;
  }
}

// ---------------- finalize: merge 4 col-block stats -> lse; convert raw logits to log-probs
__global__ void finalize_kernel(const float* __restrict__ jstats,
                                float* __restrict__ blank, float* __restrict__ lab) {
  int g = blockIdx.x * 256 + threadIdx.x;
  if (g >= B_ * RPB_) return;
  int b = g / RPB_, r = g % RPB_;
  const float* st = jstats + ((size_t)b * RPAD_ + r) * 8;
  float M = fmaxf(fmaxf(st[0], st[2]), fmaxf(st[4], st[6]));
  float s = st[1] * __expf(st[0] - M) + st[3] * __expf(st[2] - M) +
            st[5] * __expf(st[4] - M) + st[7] * __expf(st[6] - M);
  float lse = M + __logf(s);
  blank[g] -= lse;
  if ((r % U1_) < U_) lab[g] -= lse;
}

// ---------------- RNNT loss (OUTPUT IS FLOAT32)
__global__ void loss_kernel(const float* __restrict__ blank, const float* __restrict__ lab,
                            const int* __restrict__ Tl, const int* __restrict__ Ul,
                            float* __restrict__ outp) {
  int b = threadIdx.x >> 6;
  int l = threadIdx.x & 63;
  int TL = Tl[b], UL = Ul[b];
  float alpha_l = 0.f, alpha0 = 0.f;
  for (int t = 0; t < TL; ++t) {
    float a_u0, a_l1;
    if (t == 0) { a_u0 = 0.f; a_l1 = -1e30f; }
    else {
      const float* bl = blank + ((size_t)b * T_ + (t - 1)) * U1_;
      a_u0 = alpha0 + bl[0];
      a_l1 = alpha_l + bl[l + 1];
    }
    const float* lb = lab + ((size_t)b * T_ + t) * U1_;
    float C = lb[l];
#pragma unroll
    for (int dd = 1; dd < 64; dd <<= 1) {
      float o = __shfl_up(C, dd, 64);
      if (l >= dd) C += o;
    }
    float S = a_l1 - C;
#pragma unroll
    for (int dd = 1; dd < 64; dd <<= 1) {
      float o = __shfl_up(S, dd, 64);
      if (l >= dd) S = lae_(S, o);
    }
    alpha_l = C + lae_(a_u0, S);
    alpha0 = a_u0;
  }
  float av = (UL == 0) ? alpha0 : __shfl(alpha_l, UL - 1, 64);
  float ll = av + blank[((size_t)b * T_ + (TL - 1)) * U1_ + UL];
  __shared__ float lls[4];
  if (l == 0) lls[b] = ll;
  __syncthreads();
  if (threadIdx.x == 0) outp[0] = -0.25f * (lls[0] + lls[1] + lls[2] + lls[3]);
}

// ---------------- workspace layout (bytes)
static constexpr size_t OFF_XG = 0;                                        // f32 [2][4][300][2048]
static constexpr size_t OFF_XA = OFF_XG + (size_t)2 * B_ * T_ * G4_ * 4;   // bf16 [4][300][1024]
static constexpr size_t OFF_XB = OFF_XA + (size_t)B_ * T_ * 1024 * 2;
static constexpr size_t OFF_ENC = OFF_XB + (size_t)B_ * T_ * 1024 * 2;     // bf16 [4][300][512]
static constexpr size_t OFF_EA = OFF_ENC + (size_t)B_ * T_ * 512 * 2;      // f32
static constexpr size_t OFF_DEMB = OFF_EA + (size_t)B_ * T_ * 512 * 4;     // bf16
static constexpr size_t OFF_DXG = OFF_DEMB + (size_t)B_ * U1_ * 512 * 2;   // f32
static constexpr size_t OFF_DH = OFF_DXG + (size_t)B_ * U1_ * G4_ * 4;     // bf16
static constexpr size_t OFF_DEC = OFF_DH + (size_t)B_ * U1_ * 512 * 2;     // bf16
static constexpr size_t OFF_DA = OFF_DEC + (size_t)B_ * U1_ * 512 * 2;     // f32
static constexpr size_t OFF_BL = OFF_DA + (size_t)B_ * U1_ * 512 * 4;      // f32 [4][300][65]
static constexpr size_t OFF_LAB = OFF_BL + (size_t)B_ * T_ * U1_ * 4;
static constexpr size_t OFF_HBUF = OFF_LAB + (size_t)B_ * T_ * U1_ * 4;    // f32 [2][2][4][512]
static constexpr size_t OFF_BARS = OFF_HBUF + (size_t)2 * 2 * B_ * H_ * 4; // 4096 ints (7 dir-groups x 512)
static constexpr size_t OFF_JST = OFF_BARS + 4096 * 4;                     // f32 [4][19520][4][2]

extern "C" void kernel_launch(void* const* d_in, const int* in_sizes, int n_in,
                              void* d_out, int out_size, void* d_ws, size_t ws_size,
                              hipStream_t stream) {
  (void)in_sizes; (void)n_in; (void)out_size; (void)ws_size;
  const float* inputs = (const float*)d_in[0];
  const int* inputs_length = (const int*)d_in[1];
  const int* targets = (const int*)d_in[2];
  const int* targets_length = (const int*)d_in[3];
  const float* enc_Wih = (const float*)d_in[4];
  const float* enc_Whh = (const float*)d_in[5];
  const float* enc_b = (const float*)d_in[6];
  const float* enc_proj_W = (const float*)d_in[7];
  const float* enc_proj_b = (const float*)d_in[8];
  const float* dec_emb = (const float*)d_in[9];
  const float* dec_Wih = (const float*)d_in[10];
  const float* dec_Whh = (const float*)d_in[11];
  const float* dec_b = (const float*)d_in[12];
  const float* dec_proj_W = (const float*)d_in[13];
  const float* dec_proj_b = (const float*)d_in[14];
  const float* j_fwd_W = (const float*)d_in[15];
  const float* j_fwd_b = (const float*)d_in[16];
  const float* j_proj_W = (const float*)d_in[17];
  const float* j_proj_b = (const float*)d_in[18];

  char* ws = (char*)d_ws;
  float* xg = (float*)(ws + OFF_XG);
  bf16* xa = (bf16*)(ws + OFF_XA);
  bf16* xb = (bf16*)(ws + OFF_XB);
  bf16* encb = (bf16*)(ws + OFF_ENC);
  float* eab = (float*)(ws + OFF_EA);
  bf16* demb = (bf16*)(ws + OFF_DEMB);
  float* dxg = (float*)(ws + OFF_DXG);
  bf16* dh = (bf16*)(ws + OFF_DH);
  bf16* decb = (bf16*)(ws + OFF_DEC);
  float* dab = (float*)(ws + OFF_DA);
  float* blank = (float*)(ws + OFF_BL);
  float* lab = (float*)(ws + OFF_LAB);
  float* hbuf = (float*)(ws + OFF_HBUF);
  int* bars = (int*)(ws + OFF_BARS);
  float* jstats = (float*)(ws + OFF_JST);

  prep_kernel<<<600, 256, 0, stream>>>(inputs, xa, bars);
  embed_kernel<<<520, 256, 0, stream>>>(dec_emb, targets, demb);

  // decoder chain (flags group 0)
  gemm_kernel<<<dim3(5, 32), 256, 0, stream>>>(demb, 512, dec_Wih, 512, dec_b,
                                               dxg, 1, G4_, B_ * U1_, 512);
  scan_kernel<<<dim3(NW_, 1), 256, 0, stream>>>(dxg, dec_Whh, targets_length, 1, U1_, 0,
                                                dh, 512, hbuf, bars);
  gemm_kernel<<<dim3(5, 8), 256, 0, stream>>>(dh, 512, dec_proj_W, 512, dec_proj_b,
                                              decb, 0, 512, B_ * U1_, 512);
  gemm_kernel<<<dim3(5, 8), 256, 0, stream>>>(decb, 512, j_fwd_W + 512, 1024, j_fwd_b,
                                              dab, 1, 512, B_ * U1_, 512);

  // encoder: 3 BiLSTM layers (layer l flags: groups 1+2l, 2+2l)
  bf16* xcur = xa;
  for (int lyr = 0; lyr < 3; ++lyr) {
    int K = (lyr == 0) ? 128 : 1024;
    bf16* xnext = (xcur == xa) ? xb : xa;
    for (int dd = 0; dd < 2; ++dd) {
      gemm_kernel<<<dim3(19, 32), 256, 0, stream>>>(
          xcur, 1024,
          enc_Wih + (size_t)(lyr * 2 + dd) * G4_ * 1024, 1024,
          enc_b + (size_t)(lyr * 2 + dd) * G4_,
          xg + (size_t)dd * B_ * T_ * G4_, 1, G4_, B_ * T_, K);
    }
    scan_kernel<<<dim3(NW_, 2), 256, 0, stream>>>(
        xg, enc_Whh + (size_t)lyr * 2 * G4_ * H_,
        inputs_length, 0, T_, 2, xnext, 1024, hbuf, bars + 512 + lyr * 1024);
    xcur = xnext;
  }
  gemm_kernel<<<dim3(19, 8), 256, 0, stream>>>(xcur, 1024, enc_proj_W, 1024, enc_proj_b,
                                               encb, 0, 512, B_ * T_, 1024);
  gemm_kernel<<<dim3(19, 8), 256, 0, stream>>>(encb, 512, j_fwd_W, 1024, (const float*)nullptr,
                                               eab, 1, 512, B_ * T_, 512);

  joint_kernel<<<dim3(NTILE_, 4, B_), 256, 0, stream>>>(eab, dab, j_proj_W, j_proj_b, targets,
                                                        blank, lab, jstats);
  finalize_kernel<<<(B_ * RPB_ + 255) / 256, 256, 0, stream>>>(jstats, blank, lab);
  loss_kernel<<<1, 256, 0, stream>>>(blank, lab, inputs_length, targets_length, (float*)d_out);
}

// Round 7
// 5468.941 us; speedup vs baseline: 2.9463x; 1.3451x over previous
//
#include <hip/hip_runtime.h>
#include <hip/hip_bf16.h>

#define B_ 4
#define T_ 300
#define U_ 64
#define U1_ 65
#define V_ 1024
#define H_ 512
#define G4_ 2048
#define NW_ 32
#define RPB_ (T_ * U1_)   // 19500 rows per batch in joint
#define NTILE_ 305        // ceil(19500/64)
#define RPAD_ 19520       // NTILE_*64

typedef __hip_bfloat16 bf16;
typedef unsigned long long u64;
typedef __attribute__((ext_vector_type(8))) short short8;
typedef __attribute__((ext_vector_type(4))) float floatx4;

__device__ __forceinline__ float b2f(bf16 x) { return __bfloat162float(x); }
__device__ __forceinline__ bf16 f2b(float x) { return __float2bfloat16(x); }
__device__ __forceinline__ short bf16bits(float x) {
  bf16 h = __float2bfloat16(x);
  return *reinterpret_cast<short*>(&h);
}
__device__ __forceinline__ short8 pack8(float4 a, float4 b) {
  short8 p;
  p[0] = bf16bits(a.x); p[1] = bf16bits(a.y); p[2] = bf16bits(a.z); p[3] = bf16bits(a.w);
  p[4] = bf16bits(b.x); p[5] = bf16bits(b.y); p[6] = bf16bits(b.z); p[7] = bf16bits(b.w);
  return p;
}
__device__ __forceinline__ float sigm_(float x) { return 1.f / (1.f + __expf(-x)); }
__device__ __forceinline__ float tanh_(float x) { return 1.f - 2.f / (1.f + __expf(2.f * x)); }
__device__ __forceinline__ float lae_(float x, float y) {
  float m = fmaxf(x, y);
  float n = fminf(x, y);
  return m + __logf(1.f + __expf(n - m));
}

// ---------------- prep: pad layer-0 input (80 -> 128 cols of a 1024-stride buf)
__global__ void prep_kernel(const float* __restrict__ in, bf16* __restrict__ x0) {
  int i = blockIdx.x * 256 + threadIdx.x;
  if (i < B_ * T_ * 128) {
    int k = i & 127;
    int row = i >> 7;
    float v = (k < 80) ? in[row * 80 + k] : 0.f;
    x0[(size_t)row * 1024 + k] = f2b(v);
  }
}

// ---------------- embedding gather (f32 table -> bf16)
__global__ void embed_kernel(const float* __restrict__ emb, const int* __restrict__ tgt,
                             bf16* __restrict__ demb) {
  int i = blockIdx.x * 256 + threadIdx.x;
  if (i >= B_ * U1_ * 512) return;
  int k = i & 511;
  int bu = i >> 9;
  int u = bu % U1_, b = bu / U1_;
  int id = (u == 0) ? 0 : tgt[b * U_ + u - 1];
  demb[i] = f2b(emb[(size_t)id * 512 + k]);
}

// ---------------- bf16-A x f32-W MFMA GEMM: C[M x (grid.y*64)] = A[M,K] @ W[N,K]^T + bias
__global__ __launch_bounds__(256) void gemm_kernel(
    const bf16* __restrict__ A, int lda,
    const float* __restrict__ W, int ldw,
    const float* __restrict__ bias,
    void* __restrict__ Cout, int out_f32, int ldc,
    int M, int K) {
  __shared__ __align__(16) bf16 As[64][72];
  __shared__ __align__(16) bf16 Bs[64][72];
  int m0 = blockIdx.x * 64, n0 = blockIdx.y * 64;
  int tid = threadIdx.x, w = tid >> 6, l = tid & 63;
  int l4 = l & 15, lq = l >> 4;
  floatx4 acc[4];
#pragma unroll
  for (int nt = 0; nt < 4; ++nt) acc[nt] = (floatx4){0.f, 0.f, 0.f, 0.f};
  for (int k0 = 0; k0 < K; k0 += 64) {
    __syncthreads();
#pragma unroll
    for (int q = 0; q < 2; ++q) {
      int cc = tid + q * 256;
      int r = cc >> 3, kc = (cc & 7) * 8;
      short8 va = {0, 0, 0, 0, 0, 0, 0, 0};
      int gm = m0 + r;
      if (gm < M) va = *(const short8*)(A + (size_t)gm * lda + k0 + kc);
      *(short8*)(&As[r][kc]) = va;
      const float* wp = W + (size_t)(n0 + r) * ldw + k0 + kc;
      float4 w0 = *(const float4*)(wp);
      float4 w1 = *(const float4*)(wp + 4);
      *(short8*)(&Bs[r][kc]) = pack8(w0, w1);
    }
    __syncthreads();
#pragma unroll
    for (int kk = 0; kk < 64; kk += 32) {
      short8 a = *(const short8*)(&As[w * 16 + l4][kk + lq * 8]);
#pragma unroll
      for (int nt = 0; nt < 4; ++nt) {
        short8 bb = *(const short8*)(&Bs[nt * 16 + l4][kk + lq * 8]);
        acc[nt] = __builtin_amdgcn_mfma_f32_16x16x32_bf16(a, bb, acc[nt], 0, 0, 0);
      }
    }
  }
#pragma unroll
  for (int nt = 0; nt < 4; ++nt) {
    int col = n0 + nt * 16 + l4;
    float bv = bias ? bias[col] : 0.f;
#pragma unroll
    for (int r = 0; r < 4; ++r) {
      int row = m0 + w * 16 + lq * 4 + r;
      if (row < M) {
        float v = acc[nt][r] + bv;
        if (out_f32) ((float*)Cout)[(size_t)row * ldc + col] = v;
        else ((bf16*)Cout)[(size_t)row * ldc + col] = f2b(v);
      }
    }
  }
}

// ---------------- persistent LSTM scan, self-stamped b64 packet protocol.
// grid = (NW_, ndir). WG w owns h-dims [w*16,w*16+16) x 4 gates.
// Each h value is an 8B packet {stamp = s+1 (low dword), f32 h bits (high dword)}
// written by ONE relaxed agent-scope b64 atomic store (architecturally atomic).
// Consumers spin on the packets themselves: stamp fresh => payload in hand.
// Per dir: hpk + d*4096 packets; parity p at + p*2048; packet idx = b*512 + dim.
__global__ __launch_bounds__(256, 1) void scan_kernel(
    const float* __restrict__ xg,      // [ndir][B][Tmax][2048] f32
    const float* __restrict__ whh,     // [ndir][2048][512] f32
    const int* __restrict__ len_raw, int len_add,
    int Tmax, int bwd_mask,
    bf16* __restrict__ out, int out_stride,
    u64* __restrict__ hpk) {
  int w = blockIdx.x, d = blockIdx.y;
  int tid = threadIdx.x;
  const float* xg_d = xg + (size_t)d * B_ * Tmax * G4_;
  const float* whh_d = whh + (size_t)d * G4_ * H_;
  u64* hp = hpk + (size_t)d * 4096;
  bool bwd = (bwd_mask >> d) & 1;

  int row = tid & 63;          // gate = row>>4, dim = row&15
  int ks = tid >> 6;           // k-slice 0..3 (128 each)
  int grow = (row >> 4) * H_ + w * 16 + (row & 15);

  float wreg[128];
  {
    const float* wp = whh_d + (size_t)grow * H_ + ks * 128;
#pragma unroll
    for (int j = 0; j < 128; ++j) wreg[j] = wp[j];
  }

  __shared__ __align__(16) float h_lds[4][512];
  __shared__ float partial[4][64][5];
  __shared__ float gates[64][5];
  __shared__ float c_lds[16][4];
  __shared__ int len_s[4];

  if (tid < 4) len_s[tid] = len_raw[tid] + len_add;
  if (tid < 64) c_lds[tid & 15][tid >> 4] = 0.f;
  __syncthreads();
  int smax = max(max(len_s[0], len_s[1]), max(len_s[2], len_s[3]));
  int rb = tid >> 6;

  for (int s = 0; s < smax; ++s) {
    // prefetch xg value used in gates phase (independent of h)
    bool ract = s < len_s[rb];
    int rt = bwd ? (len_s[rb] - 1 - s) : s;
    if (!ract) rt = 0;
    float xv = xg_d[((size_t)rb * Tmax + rt) * G4_ + grow];

    float* hl = &h_lds[0][0];
    if (s == 0) {
      float4* dst = (float4*)hl;
      float4 z = {0.f, 0.f, 0.f, 0.f};
      dst[tid] = z;
      dst[tid + 256] = z;
    } else {
      const u64* src = hp + ((s - 1) & 1) * 2048;
      u64 v[8];
      for (;;) {
        bool ok = true;
#pragma unroll
        for (int q = 0; q < 8; ++q) {
          v[q] = __hip_atomic_load(src + tid + q * 256, __ATOMIC_RELAXED,
                                   __HIP_MEMORY_SCOPE_AGENT);
          ok &= ((int)(unsigned)v[q] == s);
        }
        if (ok) break;
        __builtin_amdgcn_s_sleep(1);
      }
#pragma unroll
      for (int q = 0; q < 8; ++q)
        hl[tid + q * 256] = __uint_as_float((unsigned)(v[q] >> 32));
    }
    __syncthreads();
    // matvec: 4 batches, b128 LDS broadcasts
    float a0 = 0.f, a1 = 0.f, a2 = 0.f, a3 = 0.f;
    {
      int kb = ks * 128;
      const float4* hb0 = (const float4*)&h_lds[0][kb];
      const float4* hb1 = (const float4*)&h_lds[1][kb];
      const float4* hb2 = (const float4*)&h_lds[2][kb];
      const float4* hb3 = (const float4*)&h_lds[3][kb];
#pragma unroll
      for (int j = 0; j < 32; ++j) {
        float w0 = wreg[4 * j], w1 = wreg[4 * j + 1], w2 = wreg[4 * j + 2], w3 = wreg[4 * j + 3];
        float4 x0 = hb0[j], x1 = hb1[j], x2 = hb2[j], x3 = hb3[j];
        a0 += w0 * x0.x + w1 * x0.y + w2 * x0.z + w3 * x0.w;
        a1 += w0 * x1.x + w1 * x1.y + w2 * x1.z + w3 * x1.w;
        a2 += w0 * x2.x + w1 * x2.y + w2 * x2.z + w3 * x2.w;
        a3 += w0 * x3.x + w1 * x3.y + w2 * x3.z + w3 * x3.w;
      }
    }
    partial[ks][row][0] = a0;
    partial[ks][row][1] = a1;
    partial[ks][row][2] = a2;
    partial[ks][row][3] = a3;
    __syncthreads();
    gates[row][rb] = partial[0][row][rb] + partial[1][row][rb] +
                     partial[2][row][rb] + partial[3][row][rb] + xv;
    __syncthreads();
    if (tid < 64) {
      int tdim = tid & 15, tbb = tid >> 4;
      bool wactive = s < len_s[tbb];
      float hval = 0.f;
      if (wactive) {
        float gi = gates[tdim][tbb];
        float gf = gates[16 + tdim][tbb];
        float gg = gates[32 + tdim][tbb];
        float go = gates[48 + tdim][tbb];
        float c = c_lds[tdim][tbb];
        c = sigm_(gf) * c + sigm_(gi) * tanh_(gg);
        hval = sigm_(go) * tanh_(c);
        c_lds[tdim][tbb] = c;
      }
      // publish stamped packet (ALWAYS, so consumers never deadlock on padded batches)
      u64 pkt = ((u64)__float_as_uint(hval) << 32) | (unsigned)(s + 1);
      __hip_atomic_store(hp + (s & 1) * 2048 + tbb * 512 + w * 16 + tdim, pkt,
                         __ATOMIC_RELAXED, __HIP_MEMORY_SCOPE_AGENT);
      // activation store off the critical path
      if (wactive) {
        int t = bwd ? (len_s[tbb] - 1 - s) : s;
        out[((size_t)tbb * Tmax + t) * out_stride + d * H_ + w * 16 + tdim] = f2b(hval);
      }
    }
  }
}

// ---------------- joint (<=48KB LDS): block = 64 rows x 256 cols, K=512.
__global__ __launch_bounds__(256) void joint_kernel(
    const float* __restrict__ ea, const float* __restrict__ da,
    const float* __restrict__ Wp, const float* __restrict__ pb,
    const int* __restrict__ targets,
    float* __restrict__ blankraw, float* __restrict__ labraw,
    float* __restrict__ jstats) {
  __shared__ __align__(16) bf16 As[64][72];
  __shared__ __align__(16) bf16 Bs[256][72];
  __shared__ float bias_s[256];
  __shared__ int tgt_s[64];
  __shared__ float pstat[64][2][2];

  int tid = threadIdx.x;
  int tile = blockIdx.x, cb = blockIdx.y, b = blockIdx.z;
  int r0 = tile * 64;

  bias_s[tid & 255] = pb[cb * 256 + (tid & 255)];
  if (tid < 64) {
    int r = r0 + tid;
    int u = r % U1_;
    tgt_s[tid] = (r < RPB_ && u < U_) ? targets[b * U_ + u] : -1;
  }
  int si = tid >> 2;
  int sseg = (tid & 3) * 16;
  int sr = r0 + si;
  bool svalid = sr < RPB_;
  int st = svalid ? sr / U1_ : 0;
  int su = svalid ? sr % U1_ : 0;
  const float* ep = ea + ((size_t)(b * T_ + st)) * 512 + sseg;
  const float* dp = da + ((size_t)(b * U1_ + su)) * 512 + sseg;

  int wid = tid >> 6, l = tid & 63;
  int wm = wid >> 1, wn = wid & 1;
  int l4 = l & 15, lq = l >> 4;

  floatx4 acc[2][8];
#pragma unroll
  for (int ms = 0; ms < 2; ++ms)
#pragma unroll
    for (int nt = 0; nt < 8; ++nt) acc[ms][nt] = (floatx4){0.f, 0.f, 0.f, 0.f};

  for (int k0 = 0; k0 < 512; k0 += 64) {
    __syncthreads();
    {
      const float* e = ep + k0;
      const float* d = dp + k0;
#pragma unroll
      for (int h = 0; h < 2; ++h) {
        float4 e0 = *(const float4*)(e + h * 8);
        float4 e1 = *(const float4*)(e + h * 8 + 4);
        float4 d0 = *(const float4*)(d + h * 8);
        float4 d1 = *(const float4*)(d + h * 8 + 4);
        short8 pk = {0, 0, 0, 0, 0, 0, 0, 0};
        if (svalid) {
          pk[0] = bf16bits(tanh_(e0.x + d0.x));
          pk[1] = bf16bits(tanh_(e0.y + d0.y));
          pk[2] = bf16bits(tanh_(e0.z + d0.z));
          pk[3] = bf16bits(tanh_(e0.w + d0.w));
          pk[4] = bf16bits(tanh_(e1.x + d1.x));
          pk[5] = bf16bits(tanh_(e1.y + d1.y));
          pk[6] = bf16bits(tanh_(e1.z + d1.z));
          pk[7] = bf16bits(tanh_(e1.w + d1.w));
        }
        *(short8*)(&As[si][sseg + h * 8]) = pk;
      }
    }
#pragma unroll
    for (int q = 0; q < 8; ++q) {
      int cc = tid + q * 256;
      int r = cc >> 3, kc = (cc & 7) * 8;
      const float* wp = Wp + (size_t)(cb * 256 + r) * 512 + k0 + kc;
      float4 w0 = *(const float4*)(wp);
      float4 w1 = *(const float4*)(wp + 4);
      *(short8*)(&Bs[r][kc]) = pack8(w0, w1);
    }
    __syncthreads();
#pragma unroll
    for (int kk = 0; kk < 64; kk += 32) {
      short8 af[2], bf8[8];
#pragma unroll
      for (int ms = 0; ms < 2; ++ms)
        af[ms] = *(const short8*)(&As[wm * 32 + ms * 16 + l4][kk + lq * 8]);
#pragma unroll
      for (int nt = 0; nt < 8; ++nt)
        bf8[nt] = *(const short8*)(&Bs[wn * 128 + nt * 16 + l4][kk + lq * 8]);
#pragma unroll
      for (int ms = 0; ms < 2; ++ms)
#pragma unroll
        for (int nt = 0; nt < 8; ++nt)
          acc[ms][nt] = __builtin_amdgcn_mfma_f32_16x16x32_bf16(af[ms], bf8[nt], acc[ms][nt], 0, 0, 0);
    }
  }
#pragma unroll
  for (int ms = 0; ms < 2; ++ms) {
#pragma unroll
    for (int r = 0; r < 4; ++r) {
      int i = wm * 32 + ms * 16 + lq * 4 + r;
      int grow = r0 + i;
      bool valid = grow < RPB_;
      int tg = tgt_s[i];
      float v[8];
      float mx = -1e30f;
#pragma unroll
      for (int nt = 0; nt < 8; ++nt) {
        int colc = wn * 128 + nt * 16 + l4;
        float x = acc[ms][nt][r] + bias_s[colc];
        v[nt] = x;
        mx = fmaxf(mx, x);
        int gcol = cb * 256 + colc;
        if (valid) {
          if (gcol == 0) blankraw[(size_t)b * RPB_ + grow] = x;
          if (gcol == tg) labraw[(size_t)b * RPB_ + grow] = x;
        }
      }
#pragma unroll
      for (int dd = 1; dd < 16; dd <<= 1) mx = fmaxf(mx, __shfl_xor(mx, dd, 64));
      float se = 0.f;
#pragma unroll
      for (int nt = 0; nt < 8; ++nt) se += __expf(v[nt] - mx);
#pragma unroll
      for (int dd = 1; dd < 16; dd <<= 1) se += __shfl_xor(se, dd, 64);
      if (l4 == 0) { pstat[i][wn][0] = mx; pstat[i][wn][1] = se; }
    }
  }
  __syncthreads();
  if (tid < 64) {
    float ma = pstat[tid][0][0], sa = pstat[tid][0][1];
    float mb = pstat[tid][1][0], sb = pstat[tid][1][1];
    float mc = fmaxf(ma, mb);
    float sc = sa * __expf(ma - mc) + sb * __expf(mb - mc);
    size_t o = (((size_t)b * RPAD_ + r0 + tid) * 4 + cb) * 2;
    jstats[o] = mc;
    jstats[o + 1] = sc;
  }
}

// ---------------- finalize: merge 4 col-block stats -> lse; convert raw logits to log-probs
__global__ void finalize_kernel(const float* __restrict__ jstats,
                                float* __restrict__ blank, float* __restrict__ lab) {
  int g = blockIdx.x * 256 + threadIdx.x;
  if (g >= B_ * RPB_) return;
  int b = g / RPB_, r = g % RPB_;
  const float* st = jstats + ((size_t)b * RPAD_ + r) * 8;
  float M = fmaxf(fmaxf(st[0], st[2]), fmaxf(st[4], st[6]));
  float s = st[1] * __expf(st[0] - M) + st[3] * __expf(st[2] - M) +
            st[5] * __expf(st[4] - M) + st[7] * __expf(st[6] - M);
  float lse = M + __logf(s);
  blank[g] -= lse;
  if ((r % U1_) < U_) lab[g] -= lse;
}

// ---------------- RNNT loss (OUTPUT IS FLOAT32)
__global__ void loss_kernel(const float* __restrict__ blank, const float* __restrict__ lab,
                            const int* __restrict__ Tl, const int* __restrict__ Ul,
                            float* __restrict__ outp) {
  int b = threadIdx.x >> 6;
  int l = threadIdx.x & 63;
  int TL = Tl[b], UL = Ul[b];
  float alpha_l = 0.f, alpha0 = 0.f;
  for (int t = 0; t < TL; ++t) {
    float a_u0, a_l1;
    if (t == 0) { a_u0 = 0.f; a_l1 = -1e30f; }
    else {
      const float* bl = blank + ((size_t)b * T_ + (t - 1)) * U1_;
      a_u0 = alpha0 + bl[0];
      a_l1 = alpha_l + bl[l + 1];
    }
    const float* lb = lab + ((size_t)b * T_ + t) * U1_;
    float C = lb[l];
#pragma unroll
    for (int dd = 1; dd < 64; dd <<= 1) {
      float o = __shfl_up(C, dd, 64);
      if (l >= dd) C += o;
    }
    float S = a_l1 - C;
#pragma unroll
    for (int dd = 1; dd < 64; dd <<= 1) {
      float o = __shfl_up(S, dd, 64);
      if (l >= dd) S = lae_(S, o);
    }
    alpha_l = C + lae_(a_u0, S);
    alpha0 = a_u0;
  }
  float av = (UL == 0) ? alpha0 : __shfl(alpha_l, UL - 1, 64);
  float ll = av + blank[((size_t)b * T_ + (TL - 1)) * U1_ + UL];
  __shared__ float lls[4];
  if (l == 0) lls[b] = ll;
  __syncthreads();
  if (threadIdx.x == 0) outp[0] = -0.25f * (lls[0] + lls[1] + lls[2] + lls[3]);
}

// ---------------- workspace layout (bytes)
static constexpr size_t OFF_XG = 0;                                        // f32 [2][4][300][2048]
static constexpr size_t OFF_XA = OFF_XG + (size_t)2 * B_ * T_ * G4_ * 4;   // bf16 [4][300][1024]
static constexpr size_t OFF_XB = OFF_XA + (size_t)B_ * T_ * 1024 * 2;
static constexpr size_t OFF_ENC = OFF_XB + (size_t)B_ * T_ * 1024 * 2;     // bf16 [4][300][512]
static constexpr size_t OFF_EA = OFF_ENC + (size_t)B_ * T_ * 512 * 2;      // f32
static constexpr size_t OFF_DEMB = OFF_EA + (size_t)B_ * T_ * 512 * 4;     // bf16
static constexpr size_t OFF_DXG = OFF_DEMB + (size_t)B_ * U1_ * 512 * 2;   // f32
static constexpr size_t OFF_DH = OFF_DXG + (size_t)B_ * U1_ * G4_ * 4;     // bf16
static constexpr size_t OFF_DEC = OFF_DH + (size_t)B_ * U1_ * 512 * 2;     // bf16
static constexpr size_t OFF_DA = OFF_DEC + (size_t)B_ * U1_ * 512 * 2;     // f32
static constexpr size_t OFF_BL = OFF_DA + (size_t)B_ * U1_ * 512 * 4;      // f32 [4][300][65]
static constexpr size_t OFF_LAB = OFF_BL + (size_t)B_ * T_ * U1_ * 4;
static constexpr size_t OFF_HPK = OFF_LAB + (size_t)B_ * T_ * U1_ * 4;     // u64 [7][2][4][512] packets
static constexpr size_t OFF_JST = OFF_HPK + (size_t)7 * 4096 * 8;          // f32 [4][19520][4][2]

extern "C" void kernel_launch(void* const* d_in, const int* in_sizes, int n_in,
                              void* d_out, int out_size, void* d_ws, size_t ws_size,
                              hipStream_t stream) {
  (void)in_sizes; (void)n_in; (void)out_size; (void)ws_size;
  const float* inputs = (const float*)d_in[0];
  const int* inputs_length = (const int*)d_in[1];
  const int* targets = (const int*)d_in[2];
  const int* targets_length = (const int*)d_in[3];
  const float* enc_Wih = (const float*)d_in[4];
  const float* enc_Whh = (const float*)d_in[5];
  const float* enc_b = (const float*)d_in[6];
  const float* enc_proj_W = (const float*)d_in[7];
  const float* enc_proj_b = (const float*)d_in[8];
  const float* dec_emb = (const float*)d_in[9];
  const float* dec_Wih = (const float*)d_in[10];
  const float* dec_Whh = (const float*)d_in[11];
  const float* dec_b = (const float*)d_in[12];
  const float* dec_proj_W = (const float*)d_in[13];
  const float* dec_proj_b = (const float*)d_in[14];
  const float* j_fwd_W = (const float*)d_in[15];
  const float* j_fwd_b = (const float*)d_in[16];
  const float* j_proj_W = (const float*)d_in[17];
  const float* j_proj_b = (const float*)d_in[18];

  char* ws = (char*)d_ws;
  float* xg = (float*)(ws + OFF_XG);
  bf16* xa = (bf16*)(ws + OFF_XA);
  bf16* xb = (bf16*)(ws + OFF_XB);
  bf16* encb = (bf16*)(ws + OFF_ENC);
  float* eab = (float*)(ws + OFF_EA);
  bf16* demb = (bf16*)(ws + OFF_DEMB);
  float* dxg = (float*)(ws + OFF_DXG);
  bf16* dh = (bf16*)(ws + OFF_DH);
  bf16* decb = (bf16*)(ws + OFF_DEC);
  float* dab = (float*)(ws + OFF_DA);
  float* blank = (float*)(ws + OFF_BL);
  float* lab = (float*)(ws + OFF_LAB);
  u64* hpk = (u64*)(ws + OFF_HPK);
  float* jstats = (float*)(ws + OFF_JST);

  prep_kernel<<<600, 256, 0, stream>>>(inputs, xa);
  embed_kernel<<<520, 256, 0, stream>>>(dec_emb, targets, demb);

  // decoder chain (packet slot 0)
  gemm_kernel<<<dim3(5, 32), 256, 0, stream>>>(demb, 512, dec_Wih, 512, dec_b,
                                               dxg, 1, G4_, B_ * U1_, 512);
  scan_kernel<<<dim3(NW_, 1), 256, 0, stream>>>(dxg, dec_Whh, targets_length, 1, U1_, 0,
                                                dh, 512, hpk);
  gemm_kernel<<<dim3(5, 8), 256, 0, stream>>>(dh, 512, dec_proj_W, 512, dec_proj_b,
                                              decb, 0, 512, B_ * U1_, 512);
  gemm_kernel<<<dim3(5, 8), 256, 0, stream>>>(decb, 512, j_fwd_W + 512, 1024, j_fwd_b,
                                              dab, 1, 512, B_ * U1_, 512);

  // encoder: 3 BiLSTM layers (layer l packet slots 1+2l, 2+2l)
  bf16* xcur = xa;
  for (int lyr = 0; lyr < 3; ++lyr) {
    int K = (lyr == 0) ? 128 : 1024;
    bf16* xnext = (xcur == xa) ? xb : xa;
    for (int dd = 0; dd < 2; ++dd) {
      gemm_kernel<<<dim3(19, 32), 256, 0, stream>>>(
          xcur, 1024,
          enc_Wih + (size_t)(lyr * 2 + dd) * G4_ * 1024, 1024,
          enc_b + (size_t)(lyr * 2 + dd) * G4_,
          xg + (size_t)dd * B_ * T_ * G4_, 1, G4_, B_ * T_, K);
    }
    scan_kernel<<<dim3(NW_, 2), 256, 0, stream>>>(
        xg, enc_Whh + (size_t)lyr * 2 * G4_ * H_,
        inputs_length, 0, T_, 2, xnext, 1024, hpk + (size_t)(1 + 2 * lyr) * 4096);
    xcur = xnext;
  }
  gemm_kernel<<<dim3(19, 8), 256, 0, stream>>>(xcur, 1024, enc_proj_W, 1024, enc_proj_b,
                                               encb, 0, 512, B_ * T_, 1024);
  gemm_kernel<<<dim3(19, 8), 256, 0, stream>>>(encb, 512, j_fwd_W, 1024, (const float*)nullptr,
                                               eab, 1, 512, B_ * T_, 512);

  joint_kernel<<<dim3(NTILE_, 4, B_), 256, 0, stream>>>(eab, dab, j_proj_W, j_proj_b, targets,
                                                        blank, lab, jstats);
  finalize_kernel<<<(B_ * RPB_ + 255) / 256, 256, 0, stream>>>(jstats, blank, lab);
  loss_kernel<<<1, 256, 0, stream>>>(blank, lab, inputs_length, targets_length, (float*)d_out);
}

// Round 8
// 5110.571 us; speedup vs baseline: 3.1529x; 1.0701x over previous
//
#include <hip/hip_runtime.h>
#include <hip/hip_bf16.h>

#define B_ 4
#define T_ 300
#define U_ 64
#define U1_ 65
#define V_ 1024
#define H_ 512
#define G4_ 2048
#define NW_ 32
#define RPB_ (T_ * U1_)   // 19500 rows per batch in joint
#define NTILE_ 305        // ceil(19500/64)
#define RPAD_ 19520       // NTILE_*64

typedef __hip_bfloat16 bf16;
typedef unsigned long long u64;
typedef __attribute__((ext_vector_type(8))) short short8;
typedef __attribute__((ext_vector_type(4))) float floatx4;

__device__ __forceinline__ float b2f(bf16 x) { return __bfloat162float(x); }
__device__ __forceinline__ bf16 f2b(float x) { return __float2bfloat16(x); }
__device__ __forceinline__ short bf16bits(float x) {
  bf16 h = __float2bfloat16(x);
  return *reinterpret_cast<short*>(&h);
}
__device__ __forceinline__ short8 pack8(float4 a, float4 b) {
  short8 p;
  p[0] = bf16bits(a.x); p[1] = bf16bits(a.y); p[2] = bf16bits(a.z); p[3] = bf16bits(a.w);
  p[4] = bf16bits(b.x); p[5] = bf16bits(b.y); p[6] = bf16bits(b.z); p[7] = bf16bits(b.w);
  return p;
}
__device__ __forceinline__ float sigm_(float x) { return 1.f / (1.f + __expf(-x)); }
__device__ __forceinline__ float tanh_(float x) { return 1.f - 2.f / (1.f + __expf(2.f * x)); }
__device__ __forceinline__ float lae_(float x, float y) {
  float m = fmaxf(x, y);
  float n = fminf(x, y);
  return m + __logf(1.f + __expf(n - m));
}

// ---------------- prep: pad layer-0 input (80 -> 128 cols of a 1024-stride buf)
__global__ void prep_kernel(const float* __restrict__ in, bf16* __restrict__ x0) {
  int i = blockIdx.x * 256 + threadIdx.x;
  if (i < B_ * T_ * 128) {
    int k = i & 127;
    int row = i >> 7;
    float v = (k < 80) ? in[row * 80 + k] : 0.f;
    x0[(size_t)row * 1024 + k] = f2b(v);
  }
}

// ---------------- embedding gather (f32 table -> bf16)
__global__ void embed_kernel(const float* __restrict__ emb, const int* __restrict__ tgt,
                             bf16* __restrict__ demb) {
  int i = blockIdx.x * 256 + threadIdx.x;
  if (i >= B_ * U1_ * 512) return;
  int k = i & 511;
  int bu = i >> 9;
  int u = bu % U1_, b = bu / U1_;
  int id = (u == 0) ? 0 : tgt[b * U_ + u - 1];
  demb[i] = f2b(emb[(size_t)id * 512 + k]);
}

// ---------------- bf16-A x f32-W MFMA GEMM: C[M x (grid.y*64)] = A[M,K] @ W[N,K]^T + bias
__global__ __launch_bounds__(256) void gemm_kernel(
    const bf16* __restrict__ A, int lda,
    const float* __restrict__ W, int ldw,
    const float* __restrict__ bias,
    void* __restrict__ Cout, int out_f32, int ldc,
    int M, int K) {
  __shared__ __align__(16) bf16 As[64][72];
  __shared__ __align__(16) bf16 Bs[64][72];
  int m0 = blockIdx.x * 64, n0 = blockIdx.y * 64;
  int tid = threadIdx.x, w = tid >> 6, l = tid & 63;
  int l4 = l & 15, lq = l >> 4;
  floatx4 acc[4];
#pragma unroll
  for (int nt = 0; nt < 4; ++nt) acc[nt] = (floatx4){0.f, 0.f, 0.f, 0.f};
  for (int k0 = 0; k0 < K; k0 += 64) {
    __syncthreads();
#pragma unroll
    for (int q = 0; q < 2; ++q) {
      int cc = tid + q * 256;
      int r = cc >> 3, kc = (cc & 7) * 8;
      short8 va = {0, 0, 0, 0, 0, 0, 0, 0};
      int gm = m0 + r;
      if (gm < M) va = *(const short8*)(A + (size_t)gm * lda + k0 + kc);
      *(short8*)(&As[r][kc]) = va;
      const float* wp = W + (size_t)(n0 + r) * ldw + k0 + kc;
      float4 w0 = *(const float4*)(wp);
      float4 w1 = *(const float4*)(wp + 4);
      *(short8*)(&Bs[r][kc]) = pack8(w0, w1);
    }
    __syncthreads();
#pragma unroll
    for (int kk = 0; kk < 64; kk += 32) {
      short8 a = *(const short8*)(&As[w * 16 + l4][kk + lq * 8]);
#pragma unroll
      for (int nt = 0; nt < 4; ++nt) {
        short8 bb = *(const short8*)(&Bs[nt * 16 + l4][kk + lq * 8]);
        acc[nt] = __builtin_amdgcn_mfma_f32_16x16x32_bf16(a, bb, acc[nt], 0, 0, 0);
      }
    }
  }
#pragma unroll
  for (int nt = 0; nt < 4; ++nt) {
    int col = n0 + nt * 16 + l4;
    float bv = bias ? bias[col] : 0.f;
#pragma unroll
    for (int r = 0; r < 4; ++r) {
      int row = m0 + w * 16 + lq * 4 + r;
      if (row < M) {
        float v = acc[nt][r] + bv;
        if (out_f32) ((float*)Cout)[(size_t)row * ldc + col] = v;
        else ((bf16*)Cout)[(size_t)row * ldc + col] = f2b(v);
      }
    }
  }
}

// ---------------- persistent LSTM scan, slice-local b64 packet protocol.
// grid = (NW_, ndir). WG w owns h-dims [w*16,w*16+16) x 4 gates.
// Wave ks polls ONLY its matvec slice's 512 packets (dims [ks*128,ks*128+128) x 4 b),
// fills its private LDS slice, matvecs immediately. One __syncthreads per step;
// partial/xv LDS double-buffered by step parity. Wave 0 fuses gate-sum + cell + publish.
// dir d == dec_d uses the second (decoder) param set.
__global__ __launch_bounds__(256, 1) void scan_kernel(
    const float* __restrict__ xg,      // [ndir][B][Tmax][2048] f32
    const float* __restrict__ whh,     // [ndir][2048][512] f32
    const int* __restrict__ len_raw, int len_add,
    int Tmax, int bwd_mask,
    bf16* __restrict__ out, int out_stride,
    int dec_d,
    const float* __restrict__ xg2, const float* __restrict__ whh2,
    const int* __restrict__ len_raw2, int len_add2,
    int Tmax2, bf16* __restrict__ out2, int out_stride2,
    u64* __restrict__ hpk) {
  int w = blockIdx.x, d = blockIdx.y;
  int tid = threadIdx.x;
  bool isdec = (d == dec_d);
  const float* xg_d = isdec ? xg2 : xg + (size_t)d * B_ * Tmax * G4_;
  const float* whh_d = isdec ? whh2 : whh + (size_t)d * G4_ * H_;
  const int* lens = isdec ? len_raw2 : len_raw;
  int ladd = isdec ? len_add2 : len_add;
  int tmax = isdec ? Tmax2 : Tmax;
  bf16* outp = isdec ? out2 : out;
  int ostride = isdec ? out_stride2 : out_stride;
  int ocol = isdec ? 0 : d * H_;
  bool bwd = isdec ? false : ((bwd_mask >> d) & 1);
  u64* hp = hpk + (size_t)d * 4096;

  int row = tid & 63;          // gate = row>>4, dim16 = row&15
  int ks = tid >> 6;           // k-slice 0..3 (128 each); wave index
  int lane = row;
  int grow = (row >> 4) * H_ + w * 16 + (row & 15);

  float wreg[128];
  {
    const float* wp = whh_d + (size_t)grow * H_ + ks * 128;
#pragma unroll
    for (int j = 0; j < 128; ++j) wreg[j] = wp[j];
  }

  __shared__ __align__(16) float h_lds[4][512];     // [b][dim], wave ks owns dims [ks*128, +128)
  __shared__ __align__(16) float partial[2][4][64][4];  // [parity][ks][row][b]
  __shared__ float xvs[2][64][4];                   // [parity][row][b(=ks)]
  __shared__ float c_lds[16][4];
  __shared__ int len_s[4];

  if (tid < 4) len_s[tid] = lens[tid] + ladd;
  if (tid < 64) c_lds[tid & 15][tid >> 4] = 0.f;
  __syncthreads();
  int smax = max(max(len_s[0], len_s[1]), max(len_s[2], len_s[3]));

  int d0 = ks * 128 + lane;    // my two slice dims
  int d1 = d0 + 64;

  for (int s = 0; s < smax; ++s) {
    int p = s & 1;
    // prefetch xg value for (row, batch=ks) — independent of h
    bool ract = s < len_s[ks];
    int rt = bwd ? (len_s[ks] - 1 - s) : s;
    if (!ract) rt = 0;
    float xv = xg_d[((size_t)ks * tmax + rt) * G4_ + grow];

    // acquire my slice of h(s-1): poll packets directly (stamp==s => payload fresh)
    if (s == 0) {
#pragma unroll
      for (int b = 0; b < 4; ++b) { h_lds[b][d0] = 0.f; h_lds[b][d1] = 0.f; }
    } else {
      const u64* src = hp + ((s - 1) & 1) * 2048;
      u64 v[8];
      for (;;) {
        bool ok = true;
#pragma unroll
        for (int b = 0; b < 4; ++b) {
          v[2 * b] = __hip_atomic_load(src + b * 512 + d0, __ATOMIC_RELAXED,
                                       __HIP_MEMORY_SCOPE_AGENT);
          v[2 * b + 1] = __hip_atomic_load(src + b * 512 + d1, __ATOMIC_RELAXED,
                                           __HIP_MEMORY_SCOPE_AGENT);
          ok &= ((int)(unsigned)v[2 * b] == s) & ((int)(unsigned)v[2 * b + 1] == s);
        }
        if (__all(ok)) break;
        __builtin_amdgcn_s_sleep(1);
      }
#pragma unroll
      for (int b = 0; b < 4; ++b) {
        h_lds[b][d0] = __uint_as_float((unsigned)(v[2 * b] >> 32));
        h_lds[b][d1] = __uint_as_float((unsigned)(v[2 * b + 1] >> 32));
      }
    }
    // matvec over own slice (same-wave ds_write->ds_read; compiler inserts lgkm waits)
    float a0 = 0.f, a1 = 0.f, a2 = 0.f, a3 = 0.f;
    {
      int kb = ks * 128;
      const float4* hb0 = (const float4*)&h_lds[0][kb];
      const float4* hb1 = (const float4*)&h_lds[1][kb];
      const float4* hb2 = (const float4*)&h_lds[2][kb];
      const float4* hb3 = (const float4*)&h_lds[3][kb];
#pragma unroll
      for (int j = 0; j < 32; ++j) {
        float w0 = wreg[4 * j], w1 = wreg[4 * j + 1], w2 = wreg[4 * j + 2], w3 = wreg[4 * j + 3];
        float4 x0 = hb0[j], x1 = hb1[j], x2 = hb2[j], x3 = hb3[j];
        a0 += w0 * x0.x + w1 * x0.y + w2 * x0.z + w3 * x0.w;
        a1 += w0 * x1.x + w1 * x1.y + w2 * x1.z + w3 * x1.w;
        a2 += w0 * x2.x + w1 * x2.y + w2 * x2.z + w3 * x2.w;
        a3 += w0 * x3.x + w1 * x3.y + w2 * x3.z + w3 * x3.w;
      }
    }
    *(float4*)&partial[p][ks][row][0] = make_float4(a0, a1, a2, a3);
    xvs[p][row][ks] = xv;
    __syncthreads();  // the ONLY per-step barrier
    if (tid < 64) {   // wave 0: gate-sum + LSTM cell + publish
      int dim = tid & 15, bb = tid >> 4;
      float g[4];
#pragma unroll
      for (int gg = 0; gg < 4; ++gg) {
        int r = gg * 16 + dim;
        g[gg] = partial[p][0][r][bb] + partial[p][1][r][bb] +
                partial[p][2][r][bb] + partial[p][3][r][bb] + xvs[p][r][bb];
      }
      bool wactive = s < len_s[bb];
      float hval = 0.f;
      if (wactive) {
        float c = c_lds[dim][bb];
        c = sigm_(g[1]) * c + sigm_(g[0]) * tanh_(g[2]);
        hval = sigm_(g[3]) * tanh_(c);
        c_lds[dim][bb] = c;
      }
      // publish stamped packet (ALWAYS, so consumers never deadlock on padded batches)
      u64 pkt = ((u64)__float_as_uint(hval) << 32) | (unsigned)(s + 1);
      __hip_atomic_store(hp + p * 2048 + bb * 512 + w * 16 + dim, pkt,
                         __ATOMIC_RELAXED, __HIP_MEMORY_SCOPE_AGENT);
      // activation store off the critical path
      if (wactive) {
        int t = bwd ? (len_s[bb] - 1 - s) : s;
        outp[((size_t)bb * tmax + t) * ostride + ocol + w * 16 + dim] = f2b(hval);
      }
    }
  }
}

// ---------------- joint (<=48KB LDS): block = 64 rows x 256 cols, K=512.
__global__ __launch_bounds__(256) void joint_kernel(
    const float* __restrict__ ea, const float* __restrict__ da,
    const float* __restrict__ Wp, const float* __restrict__ pb,
    const int* __restrict__ targets,
    float* __restrict__ blankraw, float* __restrict__ labraw,
    float* __restrict__ jstats) {
  __shared__ __align__(16) bf16 As[64][72];
  __shared__ __align__(16) bf16 Bs[256][72];
  __shared__ float bias_s[256];
  __shared__ int tgt_s[64];
  __shared__ float pstat[64][2][2];

  int tid = threadIdx.x;
  int tile = blockIdx.x, cb = blockIdx.y, b = blockIdx.z;
  int r0 = tile * 64;

  bias_s[tid & 255] = pb[cb * 256 + (tid & 255)];
  if (tid < 64) {
    int r = r0 + tid;
    int u = r % U1_;
    tgt_s[tid] = (r < RPB_ && u < U_) ? targets[b * U_ + u] : -1;
  }
  int si = tid >> 2;
  int sseg = (tid & 3) * 16;
  int sr = r0 + si;
  bool svalid = sr < RPB_;
  int st = svalid ? sr / U1_ : 0;
  int su = svalid ? sr % U1_ : 0;
  const float* ep = ea + ((size_t)(b * T_ + st)) * 512 + sseg;
  const float* dp = da + ((size_t)(b * U1_ + su)) * 512 + sseg;

  int wid = tid >> 6, l = tid & 63;
  int wm = wid >> 1, wn = wid & 1;
  int l4 = l & 15, lq = l >> 4;

  floatx4 acc[2][8];
#pragma unroll
  for (int ms = 0; ms < 2; ++ms)
#pragma unroll
    for (int nt = 0; nt < 8; ++nt) acc[ms][nt] = (floatx4){0.f, 0.f, 0.f, 0.f};

  for (int k0 = 0; k0 < 512; k0 += 64) {
    __syncthreads();
    {
      const float* e = ep + k0;
      const float* d = dp + k0;
#pragma unroll
      for (int h = 0; h < 2; ++h) {
        float4 e0 = *(const float4*)(e + h * 8);
        float4 e1 = *(const float4*)(e + h * 8 + 4);
        float4 d0 = *(const float4*)(d + h * 8);
        float4 d1 = *(const float4*)(d + h * 8 + 4);
        short8 pk = {0, 0, 0, 0, 0, 0, 0, 0};
        if (svalid) {
          pk[0] = bf16bits(tanh_(e0.x + d0.x));
          pk[1] = bf16bits(tanh_(e0.y + d0.y));
          pk[2] = bf16bits(tanh_(e0.z + d0.z));
          pk[3] = bf16bits(tanh_(e0.w + d0.w));
          pk[4] = bf16bits(tanh_(e1.x + d1.x));
          pk[5] = bf16bits(tanh_(e1.y + d1.y));
          pk[6] = bf16bits(tanh_(e1.z + d1.z));
          pk[7] = bf16bits(tanh_(e1.w + d1.w));
        }
        *(short8*)(&As[si][sseg + h * 8]) = pk;
      }
    }
#pragma unroll
    for (int q = 0; q < 8; ++q) {
      int cc = tid + q * 256;
      int r = cc >> 3, kc = (cc & 7) * 8;
      const float* wp = Wp + (size_t)(cb * 256 + r) * 512 + k0 + kc;
      float4 w0 = *(const float4*)(wp);
      float4 w1 = *(const float4*)(wp + 4);
      *(short8*)(&Bs[r][kc]) = pack8(w0, w1);
    }
    __syncthreads();
#pragma unroll
    for (int kk = 0; kk < 64; kk += 32) {
      short8 af[2], bf8[8];
#pragma unroll
      for (int ms = 0; ms < 2; ++ms)
        af[ms] = *(const short8*)(&As[wm * 32 + ms * 16 + l4][kk + lq * 8]);
#pragma unroll
      for (int nt = 0; nt < 8; ++nt)
        bf8[nt] = *(const short8*)(&Bs[wn * 128 + nt * 16 + l4][kk + lq * 8]);
#pragma unroll
      for (int ms = 0; ms < 2; ++ms)
#pragma unroll
        for (int nt = 0; nt < 8; ++nt)
          acc[ms][nt] = __builtin_amdgcn_mfma_f32_16x16x32_bf16(af[ms], bf8[nt], acc[ms][nt], 0, 0, 0);
    }
  }
#pragma unroll
  for (int ms = 0; ms < 2; ++ms) {
#pragma unroll
    for (int r = 0; r < 4; ++r) {
      int i = wm * 32 + ms * 16 + lq * 4 + r;
      int grow = r0 + i;
      bool valid = grow < RPB_;
      int tg = tgt_s[i];
      float v[8];
      float mx = -1e30f;
#pragma unroll
      for (int nt = 0; nt < 8; ++nt) {
        int colc = wn * 128 + nt * 16 + l4;
        float x = acc[ms][nt][r] + bias_s[colc];
        v[nt] = x;
        mx = fmaxf(mx, x);
        int gcol = cb * 256 + colc;
        if (valid) {
          if (gcol == 0) blankraw[(size_t)b * RPB_ + grow] = x;
          if (gcol == tg) labraw[(size_t)b * RPB_ + grow] = x;
        }
      }
#pragma unroll
      for (int dd = 1; dd < 16; dd <<= 1) mx = fmaxf(mx, __shfl_xor(mx, dd, 64));
      float se = 0.f;
#pragma unroll
      for (int nt = 0; nt < 8; ++nt) se += __expf(v[nt] - mx);
#pragma unroll
      for (int dd = 1; dd < 16; dd <<= 1) se += __shfl_xor(se, dd, 64);
      if (l4 == 0) { pstat[i][wn][0] = mx; pstat[i][wn][1] = se; }
    }
  }
  __syncthreads();
  if (tid < 64) {
    float ma = pstat[tid][0][0], sa = pstat[tid][0][1];
    float mb = pstat[tid][1][0], sb = pstat[tid][1][1];
    float mc = fmaxf(ma, mb);
    float sc = sa * __expf(ma - mc) + sb * __expf(mb - mc);
    size_t o = (((size_t)b * RPAD_ + r0 + tid) * 4 + cb) * 2;
    jstats[o] = mc;
    jstats[o + 1] = sc;
  }
}

// ---------------- finalize: merge 4 col-block stats -> lse; convert raw logits to log-probs
__global__ void finalize_kernel(const float* __restrict__ jstats,
                                float* __restrict__ blank, float* __restrict__ lab) {
  int g = blockIdx.x * 256 + threadIdx.x;
  if (g >= B_ * RPB_) return;
  int b = g / RPB_, r = g % RPB_;
  const float* st = jstats + ((size_t)b * RPAD_ + r) * 8;
  float M = fmaxf(fmaxf(st[0], st[2]), fmaxf(st[4], st[6]));
  float s = st[1] * __expf(st[0] - M) + st[3] * __expf(st[2] - M) +
            st[5] * __expf(st[4] - M) + st[7] * __expf(st[6] - M);
  float lse = M + __logf(s);
  blank[g] -= lse;
  if ((r % U1_) < U_) lab[g] -= lse;
}

// ---------------- RNNT loss (OUTPUT IS FLOAT32)
__global__ void loss_kernel(const float* __restrict__ blank, const float* __restrict__ lab,
                            const int* __restrict__ Tl, const int* __restrict__ Ul,
                            float* __restrict__ outp) {
  int b = threadIdx.x >> 6;
  int l = threadIdx.x & 63;
  int TL = Tl[b], UL = Ul[b];
  float alpha_l = 0.f, alpha0 = 0.f;
  for (int t = 0; t < TL; ++t) {
    float a_u0, a_l1;
    if (t == 0) { a_u0 = 0.f; a_l1 = -1e30f; }
    else {
      const float* bl = blank + ((size_t)b * T_ + (t - 1)) * U1_;
      a_u0 = alpha0 + bl[0];
      a_l1 = alpha_l + bl[l + 1];
    }
    const float* lb = lab + ((size_t)b * T_ + t) * U1_;
    float C = lb[l];
#pragma unroll
    for (int dd = 1; dd < 64; dd <<= 1) {
      float o = __shfl_up(C, dd, 64);
      if (l >= dd) C += o;
    }
    float S = a_l1 - C;
#pragma unroll
    for (int dd = 1; dd < 64; dd <<= 1) {
      float o = __shfl_up(S, dd, 64);
      if (l >= dd) S = lae_(S, o);
    }
    alpha_l = C + lae_(a_u0, S);
    alpha0 = a_u0;
  }
  float av = (UL == 0) ? alpha0 : __shfl(alpha_l, UL - 1, 64);
  float ll = av + blank[((size_t)b * T_ + (TL - 1)) * U1_ + UL];
  __shared__ float lls[4];
  if (l == 0) lls[b] = ll;
  __syncthreads();
  if (threadIdx.x == 0) outp[0] = -0.25f * (lls[0] + lls[1] + lls[2] + lls[3]);
}

// ---------------- workspace layout (bytes)
static constexpr size_t OFF_XG = 0;                                        // f32 [2][4][300][2048]
static constexpr size_t OFF_XA = OFF_XG + (size_t)2 * B_ * T_ * G4_ * 4;   // bf16 [4][300][1024]
static constexpr size_t OFF_XB = OFF_XA + (size_t)B_ * T_ * 1024 * 2;
static constexpr size_t OFF_ENC = OFF_XB + (size_t)B_ * T_ * 1024 * 2;     // bf16 [4][300][512]
static constexpr size_t OFF_EA = OFF_ENC + (size_t)B_ * T_ * 512 * 2;      // f32
static constexpr size_t OFF_DEMB = OFF_EA + (size_t)B_ * T_ * 512 * 4;     // bf16
static constexpr size_t OFF_DXG = OFF_DEMB + (size_t)B_ * U1_ * 512 * 2;   // f32
static constexpr size_t OFF_DH = OFF_DXG + (size_t)B_ * U1_ * G4_ * 4;     // bf16
static constexpr size_t OFF_DEC = OFF_DH + (size_t)B_ * U1_ * 512 * 2;     // bf16
static constexpr size_t OFF_DA = OFF_DEC + (size_t)B_ * U1_ * 512 * 2;     // f32
static constexpr size_t OFF_BL = OFF_DA + (size_t)B_ * U1_ * 512 * 4;      // f32 [4][300][65]
static constexpr size_t OFF_LAB = OFF_BL + (size_t)B_ * T_ * U1_ * 4;
static constexpr size_t OFF_HPK = OFF_LAB + (size_t)B_ * T_ * U1_ * 4;     // u64 [7][2][4][512] packets
static constexpr size_t OFF_JST = OFF_HPK + (size_t)7 * 4096 * 8;          // f32 [4][19520][4][2]

extern "C" void kernel_launch(void* const* d_in, const int* in_sizes, int n_in,
                              void* d_out, int out_size, void* d_ws, size_t ws_size,
                              hipStream_t stream) {
  (void)in_sizes; (void)n_in; (void)out_size; (void)ws_size;
  const float* inputs = (const float*)d_in[0];
  const int* inputs_length = (const int*)d_in[1];
  const int* targets = (const int*)d_in[2];
  const int* targets_length = (const int*)d_in[3];
  const float* enc_Wih = (const float*)d_in[4];
  const float* enc_Whh = (const float*)d_in[5];
  const float* enc_b = (const float*)d_in[6];
  const float* enc_proj_W = (const float*)d_in[7];
  const float* enc_proj_b = (const float*)d_in[8];
  const float* dec_emb = (const float*)d_in[9];
  const float* dec_Wih = (const float*)d_in[10];
  const float* dec_Whh = (const float*)d_in[11];
  const float* dec_b = (const float*)d_in[12];
  const float* dec_proj_W = (const float*)d_in[13];
  const float* dec_proj_b = (const float*)d_in[14];
  const float* j_fwd_W = (const float*)d_in[15];
  const float* j_fwd_b = (const float*)d_in[16];
  const float* j_proj_W = (const float*)d_in[17];
  const float* j_proj_b = (const float*)d_in[18];

  char* ws = (char*)d_ws;
  float* xg = (float*)(ws + OFF_XG);
  bf16* xa = (bf16*)(ws + OFF_XA);
  bf16* xb = (bf16*)(ws + OFF_XB);
  bf16* encb = (bf16*)(ws + OFF_ENC);
  float* eab = (float*)(ws + OFF_EA);
  bf16* demb = (bf16*)(ws + OFF_DEMB);
  float* dxg = (float*)(ws + OFF_DXG);
  bf16* dh = (bf16*)(ws + OFF_DH);
  bf16* decb = (bf16*)(ws + OFF_DEC);
  float* dab = (float*)(ws + OFF_DA);
  float* blank = (float*)(ws + OFF_BL);
  float* lab = (float*)(ws + OFF_LAB);
  u64* hpk = (u64*)(ws + OFF_HPK);
  float* jstats = (float*)(ws + OFF_JST);

  prep_kernel<<<600, 256, 0, stream>>>(inputs, xa);
  embed_kernel<<<520, 256, 0, stream>>>(dec_emb, targets, demb);

  // pre-scan GEMMs: decoder xg, then encoder layer-0 xg (both dirs)
  gemm_kernel<<<dim3(5, 32), 256, 0, stream>>>(demb, 512, dec_Wih, 512, dec_b,
                                               dxg, 1, G4_, B_ * U1_, 512);
  for (int dd = 0; dd < 2; ++dd) {
    gemm_kernel<<<dim3(19, 32), 256, 0, stream>>>(
        xa, 1024, enc_Wih + (size_t)dd * G4_ * 1024, 1024, enc_b + (size_t)dd * G4_,
        xg + (size_t)dd * B_ * T_ * G4_, 1, G4_, B_ * T_, 128);
  }
  // fused scan: dirs 0,1 = encoder layer 0; dir 2 = decoder (packet slots 0..2)
  scan_kernel<<<dim3(NW_, 3), 256, 0, stream>>>(
      xg, enc_Whh, inputs_length, 0, T_, 2, xb, 1024,
      2, dxg, dec_Whh, targets_length, 1, U1_, dh, 512,
      hpk);

  // decoder tail
  gemm_kernel<<<dim3(5, 8), 256, 0, stream>>>(dh, 512, dec_proj_W, 512, dec_proj_b,
                                              decb, 0, 512, B_ * U1_, 512);
  gemm_kernel<<<dim3(5, 8), 256, 0, stream>>>(decb, 512, j_fwd_W + 512, 1024, j_fwd_b,
                                              dab, 1, 512, B_ * U1_, 512);

  // encoder layers 1,2 (packet slots 3,4 and 5,6)
  bf16* xcur = xb;
  for (int lyr = 1; lyr < 3; ++lyr) {
    bf16* xnext = (xcur == xa) ? xb : xa;
    for (int dd = 0; dd < 2; ++dd) {
      gemm_kernel<<<dim3(19, 32), 256, 0, stream>>>(
          xcur, 1024,
          enc_Wih + (size_t)(lyr * 2 + dd) * G4_ * 1024, 1024,
          enc_b + (size_t)(lyr * 2 + dd) * G4_,
          xg + (size_t)dd * B_ * T_ * G4_, 1, G4_, B_ * T_, 1024);
    }
    scan_kernel<<<dim3(NW_, 2), 256, 0, stream>>>(
        xg, enc_Whh + (size_t)lyr * 2 * G4_ * H_,
        inputs_length, 0, T_, 2, xnext, 1024,
        -1, dxg, dec_Whh, targets_length, 1, U1_, dh, 512,
        hpk + (size_t)(3 + 2 * (lyr - 1)) * 4096);
    xcur = xnext;
  }
  gemm_kernel<<<dim3(19, 8), 256, 0, stream>>>(xcur, 1024, enc_proj_W, 1024, enc_proj_b,
                                               encb, 0, 512, B_ * T_, 1024);
  gemm_kernel<<<dim3(19, 8), 256, 0, stream>>>(encb, 512, j_fwd_W, 1024, (const float*)nullptr,
                                               eab, 1, 512, B_ * T_, 512);

  joint_kernel<<<dim3(NTILE_, 4, B_), 256, 0, stream>>>(eab, dab, j_proj_W, j_proj_b, targets,
                                                        blank, lab, jstats);
  finalize_kernel<<<(B_ * RPB_ + 255) / 256, 256, 0, stream>>>(jstats, blank, lab);
  loss_kernel<<<1, 256, 0, stream>>>(blank, lab, inputs_length, targets_length, (float*)d_out);
}

// Round 9
// 4140.403 us; speedup vs baseline: 3.8916x; 1.2343x over previous
//
#include <hip/hip_runtime.h>
#include <hip/hip_bf16.h>

#define B_ 4
#define T_ 300
#define U_ 64
#define U1_ 65
#define V_ 1024
#define H_ 512
#define G4_ 2048
#define NW_ 32
#define RPB_ (T_ * U1_)   // 19500 rows per batch in joint
#define NTILE_ 305        // ceil(19500/64)
#define RPAD_ 19520       // NTILE_*64

typedef __hip_bfloat16 bf16;
typedef unsigned long long u64;
typedef __attribute__((ext_vector_type(8))) short short8;
typedef __attribute__((ext_vector_type(4))) float floatx4;

__device__ __forceinline__ float b2f(bf16 x) { return __bfloat162float(x); }
__device__ __forceinline__ bf16 f2b(float x) { return __float2bfloat16(x); }
__device__ __forceinline__ short bf16bits(float x) {
  bf16 h = __float2bfloat16(x);
  return *reinterpret_cast<short*>(&h);
}
__device__ __forceinline__ short8 pack8(float4 a, float4 b) {
  short8 p;
  p[0] = bf16bits(a.x); p[1] = bf16bits(a.y); p[2] = bf16bits(a.z); p[3] = bf16bits(a.w);
  p[4] = bf16bits(b.x); p[5] = bf16bits(b.y); p[6] = bf16bits(b.z); p[7] = bf16bits(b.w);
  return p;
}
__device__ __forceinline__ float sigm_(float x) { return 1.f / (1.f + __expf(-x)); }
__device__ __forceinline__ float tanh_(float x) { return 1.f - 2.f / (1.f + __expf(2.f * x)); }
__device__ __forceinline__ float lae_(float x, float y) {
  float m = fmaxf(x, y);
  float n = fminf(x, y);
  return m + __logf(1.f + __expf(n - m));
}

// ---------------- prep: pad layer-0 input (80 -> 128 cols of a 1024-stride buf)
__global__ void prep_kernel(const float* __restrict__ in, bf16* __restrict__ x0) {
  int i = blockIdx.x * 256 + threadIdx.x;
  if (i < B_ * T_ * 128) {
    int k = i & 127;
    int row = i >> 7;
    float v = (k < 80) ? in[row * 80 + k] : 0.f;
    x0[(size_t)row * 1024 + k] = f2b(v);
  }
}

// ---------------- embedding gather (f32 table -> bf16)
__global__ void embed_kernel(const float* __restrict__ emb, const int* __restrict__ tgt,
                             bf16* __restrict__ demb) {
  int i = blockIdx.x * 256 + threadIdx.x;
  if (i >= B_ * U1_ * 512) return;
  int k = i & 511;
  int bu = i >> 9;
  int u = bu % U1_, b = bu / U1_;
  int id = (u == 0) ? 0 : tgt[b * U_ + u - 1];
  demb[i] = f2b(emb[(size_t)id * 512 + k]);
}

// ---------------- bf16-A x f32-W MFMA GEMM: C[M x (grid.y*64)] = A[M,K] @ W[N,K]^T + bias
__global__ __launch_bounds__(256) void gemm_kernel(
    const bf16* __restrict__ A, int lda,
    const float* __restrict__ W, int ldw,
    const float* __restrict__ bias,
    void* __restrict__ Cout, int out_f32, int ldc,
    int M, int K) {
  __shared__ __align__(16) bf16 As[64][72];
  __shared__ __align__(16) bf16 Bs[64][72];
  int m0 = blockIdx.x * 64, n0 = blockIdx.y * 64;
  int tid = threadIdx.x, w = tid >> 6, l = tid & 63;
  int l4 = l & 15, lq = l >> 4;
  floatx4 acc[4];
#pragma unroll
  for (int nt = 0; nt < 4; ++nt) acc[nt] = (floatx4){0.f, 0.f, 0.f, 0.f};
  for (int k0 = 0; k0 < K; k0 += 64) {
    __syncthreads();
#pragma unroll
    for (int q = 0; q < 2; ++q) {
      int cc = tid + q * 256;
      int r = cc >> 3, kc = (cc & 7) * 8;
      short8 va = {0, 0, 0, 0, 0, 0, 0, 0};
      int gm = m0 + r;
      if (gm < M) va = *(const short8*)(A + (size_t)gm * lda + k0 + kc);
      *(short8*)(&As[r][kc]) = va;
      const float* wp = W + (size_t)(n0 + r) * ldw + k0 + kc;
      float4 w0 = *(const float4*)(wp);
      float4 w1 = *(const float4*)(wp + 4);
      *(short8*)(&Bs[r][kc]) = pack8(w0, w1);
    }
    __syncthreads();
#pragma unroll
    for (int kk = 0; kk < 64; kk += 32) {
      short8 a = *(const short8*)(&As[w * 16 + l4][kk + lq * 8]);
#pragma unroll
      for (int nt = 0; nt < 4; ++nt) {
        short8 bb = *(const short8*)(&Bs[nt * 16 + l4][kk + lq * 8]);
        acc[nt] = __builtin_amdgcn_mfma_f32_16x16x32_bf16(a, bb, acc[nt], 0, 0, 0);
      }
    }
  }
#pragma unroll
  for (int nt = 0; nt < 4; ++nt) {
    int col = n0 + nt * 16 + l4;
    float bv = bias ? bias[col] : 0.f;
#pragma unroll
    for (int r = 0; r < 4; ++r) {
      int row = m0 + w * 16 + lq * 4 + r;
      if (row < M) {
        float v = acc[nt][r] + bv;
        if (out_f32) ((float*)Cout)[(size_t)row * ldc + col] = v;
        else ((bf16*)Cout)[(size_t)row * ldc + col] = f2b(v);
      }
    }
  }
}

// ---------------- persistent LSTM scan, slice-local b64 packet protocol.
// grid = (NW_, ndir). WG w owns h-dims [w*16,w*16+16) x 4 gates.
// Wave ks polls ONLY its matvec slice's 512 packets; fills its private LDS slice;
// matvecs immediately. One __syncthreads per step; partials transposed+padded
// (conflict-free reduce). Wave 0 fuses gate-sum + cell + publish. Hot spin (no sleep).
__global__ __launch_bounds__(256, 1) void scan_kernel(
    const float* __restrict__ xg,      // [ndir][B][Tmax][2048] f32
    const float* __restrict__ whh,     // [ndir][2048][512] f32
    const int* __restrict__ len_raw, int len_add,
    int Tmax, int bwd_mask,
    bf16* __restrict__ out, int out_stride,
    int dec_d,
    const float* __restrict__ xg2, const float* __restrict__ whh2,
    const int* __restrict__ len_raw2, int len_add2,
    int Tmax2, bf16* __restrict__ out2, int out_stride2,
    u64* __restrict__ hpk) {
  int w = blockIdx.x, d = blockIdx.y;
  int tid = threadIdx.x;
  bool isdec = (d == dec_d);
  const float* xg_d = isdec ? xg2 : xg + (size_t)d * B_ * Tmax * G4_;
  const float* whh_d = isdec ? whh2 : whh + (size_t)d * G4_ * H_;
  const int* lens = isdec ? len_raw2 : len_raw;
  int ladd = isdec ? len_add2 : len_add;
  int tmax = isdec ? Tmax2 : Tmax;
  bf16* outp = isdec ? out2 : out;
  int ostride = isdec ? out_stride2 : out_stride;
  int ocol = isdec ? 0 : d * H_;
  bool bwd = isdec ? false : ((bwd_mask >> d) & 1);
  u64* hp = hpk + (size_t)d * 4096;

  int row = tid & 63;          // gate = row>>4, dim16 = row&15
  int ks = tid >> 6;           // k-slice 0..3 (128 each); wave index
  int lane = row;
  int grow = (row >> 4) * H_ + w * 16 + (row & 15);

  float wreg[128];
  {
    const float* wp = whh_d + (size_t)grow * H_ + ks * 128;
#pragma unroll
    for (int j = 0; j < 128; ++j) wreg[j] = wp[j];
  }

  __shared__ __align__(16) float h_lds[4][512];   // [b][dim], wave ks owns dims [ks*128, +128)
  __shared__ float partialT[2][4][4][68];         // [parity][b][ks][row pad68] - conflict-free
  __shared__ float xvsT[2][4][68];                // [parity][b(=ks)][row pad68]
  __shared__ float c_lds[16][4];
  __shared__ int len_s[4];

  if (tid < 4) len_s[tid] = lens[tid] + ladd;
  if (tid < 64) c_lds[tid & 15][tid >> 4] = 0.f;
  __syncthreads();
  int smax = max(max(len_s[0], len_s[1]), max(len_s[2], len_s[3]));

  int d0 = ks * 128 + lane;    // my two slice dims
  int d1 = d0 + 64;

  for (int s = 0; s < smax; ++s) {
    int p = s & 1;
    // prefetch xg value for (row, batch=ks) — independent of h
    bool ract = s < len_s[ks];
    int rt = bwd ? (len_s[ks] - 1 - s) : s;
    if (!ract) rt = 0;
    float xv = xg_d[((size_t)ks * tmax + rt) * G4_ + grow];

    // acquire my slice of h(s-1): poll packets directly (stamp==s => payload fresh)
    if (s == 0) {
#pragma unroll
      for (int b = 0; b < 4; ++b) { h_lds[b][d0] = 0.f; h_lds[b][d1] = 0.f; }
    } else {
      const u64* src = hp + ((s - 1) & 1) * 2048;
      u64 v[8];
      for (;;) {
        bool ok = true;
#pragma unroll
        for (int b = 0; b < 4; ++b) {
          v[2 * b] = __hip_atomic_load(src + b * 512 + d0, __ATOMIC_RELAXED,
                                       __HIP_MEMORY_SCOPE_AGENT);
          v[2 * b + 1] = __hip_atomic_load(src + b * 512 + d1, __ATOMIC_RELAXED,
                                           __HIP_MEMORY_SCOPE_AGENT);
          ok &= ((int)(unsigned)v[2 * b] == s) & ((int)(unsigned)v[2 * b + 1] == s);
        }
        if (__all(ok)) break;  // hot spin: 8-load round trip is natural backoff
      }
#pragma unroll
      for (int b = 0; b < 4; ++b) {
        h_lds[b][d0] = __uint_as_float((unsigned)(v[2 * b] >> 32));
        h_lds[b][d1] = __uint_as_float((unsigned)(v[2 * b + 1] >> 32));
      }
    }
    xvsT[p][ks][row] = xv;
    // matvec over own slice (same-wave ds_write->ds_read; compiler inserts lgkm waits)
    float a0 = 0.f, a1 = 0.f, a2 = 0.f, a3 = 0.f;
    {
      int kb = ks * 128;
      const float4* hb0 = (const float4*)&h_lds[0][kb];
      const float4* hb1 = (const float4*)&h_lds[1][kb];
      const float4* hb2 = (const float4*)&h_lds[2][kb];
      const float4* hb3 = (const float4*)&h_lds[3][kb];
#pragma unroll
      for (int j = 0; j < 32; ++j) {
        float w0 = wreg[4 * j], w1 = wreg[4 * j + 1], w2 = wreg[4 * j + 2], w3 = wreg[4 * j + 3];
        float4 x0 = hb0[j], x1 = hb1[j], x2 = hb2[j], x3 = hb3[j];
        a0 += w0 * x0.x + w1 * x0.y + w2 * x0.z + w3 * x0.w;
        a1 += w0 * x1.x + w1 * x1.y + w2 * x1.z + w3 * x1.w;
        a2 += w0 * x2.x + w1 * x2.y + w2 * x2.z + w3 * x2.w;
        a3 += w0 * x3.x + w1 * x3.y + w2 * x3.z + w3 * x3.w;
      }
    }
    partialT[p][0][ks][row] = a0;
    partialT[p][1][ks][row] = a1;
    partialT[p][2][ks][row] = a2;
    partialT[p][3][ks][row] = a3;
    __syncthreads();  // the ONLY per-step barrier
    if (tid < 64) {   // wave 0: gate-sum + LSTM cell + publish
      int dim = tid & 15, bb = tid >> 4;
      float g[4];
#pragma unroll
      for (int gg = 0; gg < 4; ++gg) {
        int r = gg * 16 + dim;
        g[gg] = partialT[p][bb][0][r] + partialT[p][bb][1][r] +
                partialT[p][bb][2][r] + partialT[p][bb][3][r] + xvsT[p][bb][r];
      }
      bool wactive = s < len_s[bb];
      float hval = 0.f;
      if (wactive) {
        float c = c_lds[dim][bb];
        c = sigm_(g[1]) * c + sigm_(g[0]) * tanh_(g[2]);
        hval = sigm_(g[3]) * tanh_(c);
        c_lds[dim][bb] = c;
      }
      // publish stamped packet (ALWAYS, so consumers never deadlock on padded batches)
      u64 pkt = ((u64)__float_as_uint(hval) << 32) | (unsigned)(s + 1);
      __hip_atomic_store(hp + p * 2048 + bb * 512 + w * 16 + dim, pkt,
                         __ATOMIC_RELAXED, __HIP_MEMORY_SCOPE_AGENT);
      // activation store off the critical path
      if (wactive) {
        int t = bwd ? (len_s[bb] - 1 - s) : s;
        outp[((size_t)bb * tmax + t) * ostride + ocol + w * 16 + dim] = f2b(hval);
      }
    }
  }
}

// ---------------- joint (<=48KB LDS): block = 64 rows x 256 cols, K=512.
__global__ __launch_bounds__(256) void joint_kernel(
    const float* __restrict__ ea, const float* __restrict__ da,
    const float* __restrict__ Wp, const float* __restrict__ pb,
    const int* __restrict__ targets,
    float* __restrict__ blankraw, float* __restrict__ labraw,
    float* __restrict__ jstats) {
  __shared__ __align__(16) bf16 As[64][72];
  __shared__ __align__(16) bf16 Bs[256][72];
  __shared__ float bias_s[256];
  __shared__ int tgt_s[64];
  __shared__ float pstat[64][2][2];

  int tid = threadIdx.x;
  int tile = blockIdx.x, cb = blockIdx.y, b = blockIdx.z;
  int r0 = tile * 64;

  bias_s[tid & 255] = pb[cb * 256 + (tid & 255)];
  if (tid < 64) {
    int r = r0 + tid;
    int u = r % U1_;
    tgt_s[tid] = (r < RPB_ && u < U_) ? targets[b * U_ + u] : -1;
  }
  int si = tid >> 2;
  int sseg = (tid & 3) * 16;
  int sr = r0 + si;
  bool svalid = sr < RPB_;
  int st = svalid ? sr / U1_ : 0;
  int su = svalid ? sr % U1_ : 0;
  const float* ep = ea + ((size_t)(b * T_ + st)) * 512 + sseg;
  const float* dp = da + ((size_t)(b * U1_ + su)) * 512 + sseg;

  int wid = tid >> 6, l = tid & 63;
  int wm = wid >> 1, wn = wid & 1;
  int l4 = l & 15, lq = l >> 4;

  floatx4 acc[2][8];
#pragma unroll
  for (int ms = 0; ms < 2; ++ms)
#pragma unroll
    for (int nt = 0; nt < 8; ++nt) acc[ms][nt] = (floatx4){0.f, 0.f, 0.f, 0.f};

  for (int k0 = 0; k0 < 512; k0 += 64) {
    __syncthreads();
    {
      const float* e = ep + k0;
      const float* d = dp + k0;
#pragma unroll
      for (int h = 0; h < 2; ++h) {
        float4 e0 = *(const float4*)(e + h * 8);
        float4 e1 = *(const float4*)(e + h * 8 + 4);
        float4 d0 = *(const float4*)(d + h * 8);
        float4 d1 = *(const float4*)(d + h * 8 + 4);
        short8 pk = {0, 0, 0, 0, 0, 0, 0, 0};
        if (svalid) {
          pk[0] = bf16bits(tanh_(e0.x + d0.x));
          pk[1] = bf16bits(tanh_(e0.y + d0.y));
          pk[2] = bf16bits(tanh_(e0.z + d0.z));
          pk[3] = bf16bits(tanh_(e0.w + d0.w));
          pk[4] = bf16bits(tanh_(e1.x + d1.x));
          pk[5] = bf16bits(tanh_(e1.y + d1.y));
          pk[6] = bf16bits(tanh_(e1.z + d1.z));
          pk[7] = bf16bits(tanh_(e1.w + d1.w));
        }
        *(short8*)(&As[si][sseg + h * 8]) = pk;
      }
    }
#pragma unroll
    for (int q = 0; q < 8; ++q) {
      int cc = tid + q * 256;
      int r = cc >> 3, kc = (cc & 7) * 8;
      const float* wp = Wp + (size_t)(cb * 256 + r) * 512 + k0 + kc;
      float4 w0 = *(const float4*)(wp);
      float4 w1 = *(const float4*)(wp + 4);
      *(short8*)(&Bs[r][kc]) = pack8(w0, w1);
    }
    __syncthreads();
#pragma unroll
    for (int kk = 0; kk < 64; kk += 32) {
      short8 af[2], bf8[8];
#pragma unroll
      for (int ms = 0; ms < 2; ++ms)
        af[ms] = *(const short8*)(&As[wm * 32 + ms * 16 + l4][kk + lq * 8]);
#pragma unroll
      for (int nt = 0; nt < 8; ++nt)
        bf8[nt] = *(const short8*)(&Bs[wn * 128 + nt * 16 + l4][kk + lq * 8]);
#pragma unroll
      for (int ms = 0; ms < 2; ++ms)
#pragma unroll
        for (int nt = 0; nt < 8; ++nt)
          acc[ms][nt] = __builtin_amdgcn_mfma_f32_16x16x32_bf16(af[ms], bf8[nt], acc[ms][nt], 0, 0, 0);
    }
  }
#pragma unroll
  for (int ms = 0; ms < 2; ++ms) {
#pragma unroll
    for (int r = 0; r < 4; ++r) {
      int i = wm * 32 + ms * 16 + lq * 4 + r;
      int grow = r0 + i;
      bool valid = grow < RPB_;
      int tg = tgt_s[i];
      float v[8];
      float mx = -1e30f;
#pragma unroll
      for (int nt = 0; nt < 8; ++nt) {
        int colc = wn * 128 + nt * 16 + l4;
        float x = acc[ms][nt][r] + bias_s[colc];
        v[nt] = x;
        mx = fmaxf(mx, x);
        int gcol = cb * 256 + colc;
        if (valid) {
          if (gcol == 0) blankraw[(size_t)b * RPB_ + grow] = x;
          if (gcol == tg) labraw[(size_t)b * RPB_ + grow] = x;
        }
      }
#pragma unroll
      for (int dd = 1; dd < 16; dd <<= 1) mx = fmaxf(mx, __shfl_xor(mx, dd, 64));
      float se = 0.f;
#pragma unroll
      for (int nt = 0; nt < 8; ++nt) se += __expf(v[nt] - mx);
#pragma unroll
      for (int dd = 1; dd < 16; dd <<= 1) se += __shfl_xor(se, dd, 64);
      if (l4 == 0) { pstat[i][wn][0] = mx; pstat[i][wn][1] = se; }
    }
  }
  __syncthreads();
  if (tid < 64) {
    float ma = pstat[tid][0][0], sa = pstat[tid][0][1];
    float mb = pstat[tid][1][0], sb = pstat[tid][1][1];
    float mc = fmaxf(ma, mb);
    float sc = sa * __expf(ma - mc) + sb * __expf(mb - mc);
    size_t o = (((size_t)b * RPAD_ + r0 + tid) * 4 + cb) * 2;
    jstats[o] = mc;
    jstats[o + 1] = sc;
  }
}

// ---------------- finalize: merge 4 col-block stats -> lse; convert raw logits to log-probs
__global__ void finalize_kernel(const float* __restrict__ jstats,
                                float* __restrict__ blank, float* __restrict__ lab) {
  int g = blockIdx.x * 256 + threadIdx.x;
  if (g >= B_ * RPB_) return;
  int b = g / RPB_, r = g % RPB_;
  const float* st = jstats + ((size_t)b * RPAD_ + r) * 8;
  float M = fmaxf(fmaxf(st[0], st[2]), fmaxf(st[4], st[6]));
  float s = st[1] * __expf(st[0] - M) + st[3] * __expf(st[2] - M) +
            st[5] * __expf(st[4] - M) + st[7] * __expf(st[6] - M);
  float lse = M + __logf(s);
  blank[g] -= lse;
  if ((r % U1_) < U_) lab[g] -= lse;
}

// ---------------- RNNT loss (OUTPUT IS FLOAT32)
__global__ void loss_kernel(const float* __restrict__ blank, const float* __restrict__ lab,
                            const int* __restrict__ Tl, const int* __restrict__ Ul,
                            float* __restrict__ outp) {
  int b = threadIdx.x >> 6;
  int l = threadIdx.x & 63;
  int TL = Tl[b], UL = Ul[b];
  float alpha_l = 0.f, alpha0 = 0.f;
  for (int t = 0; t < TL; ++t) {
    float a_u0, a_l1;
    if (t == 0) { a_u0 = 0.f; a_l1 = -1e30f; }
    else {
      const float* bl = blank + ((size_t)b * T_ + (t - 1)) * U1_;
      a_u0 = alpha0 + bl[0];
      a_l1 = alpha_l + bl[l + 1];
    }
    const float* lb = lab + ((size_t)b * T_ + t) * U1_;
    float C = lb[l];
#pragma unroll
    for (int dd = 1; dd < 64; dd <<= 1) {
      float o = __shfl_up(C, dd, 64);
      if (l >= dd) C += o;
    }
    float S = a_l1 - C;
#pragma unroll
    for (int dd = 1; dd < 64; dd <<= 1) {
      float o = __shfl_up(S, dd, 64);
      if (l >= dd) S = lae_(S, o);
    }
    alpha_l = C + lae_(a_u0, S);
    alpha0 = a_u0;
  }
  float av = (UL == 0) ? alpha0 : __shfl(alpha_l, UL - 1, 64);
  float ll = av + blank[((size_t)b * T_ + (TL - 1)) * U1_ + UL];
  __shared__ float lls[4];
  if (l == 0) lls[b] = ll;
  __syncthreads();
  if (threadIdx.x == 0) outp[0] = -0.25f * (lls[0] + lls[1] + lls[2] + lls[3]);
}

// ---------------- workspace layout (bytes)
static constexpr size_t OFF_XG = 0;                                        // f32 [2][4][300][2048]
static constexpr size_t OFF_XA = OFF_XG + (size_t)2 * B_ * T_ * G4_ * 4;   // bf16 [4][300][1024]
static constexpr size_t OFF_XB = OFF_XA + (size_t)B_ * T_ * 1024 * 2;
static constexpr size_t OFF_ENC = OFF_XB + (size_t)B_ * T_ * 1024 * 2;     // bf16 [4][300][512]
static constexpr size_t OFF_EA = OFF_ENC + (size_t)B_ * T_ * 512 * 2;      // f32
static constexpr size_t OFF_DEMB = OFF_EA + (size_t)B_ * T_ * 512 * 4;     // bf16
static constexpr size_t OFF_DXG = OFF_DEMB + (size_t)B_ * U1_ * 512 * 2;   // f32
static constexpr size_t OFF_DH = OFF_DXG + (size_t)B_ * U1_ * G4_ * 4;     // bf16
static constexpr size_t OFF_DEC = OFF_DH + (size_t)B_ * U1_ * 512 * 2;     // bf16
static constexpr size_t OFF_DA = OFF_DEC + (size_t)B_ * U1_ * 512 * 2;     // f32
static constexpr size_t OFF_BL = OFF_DA + (size_t)B_ * U1_ * 512 * 4;      // f32 [4][300][65]
static constexpr size_t OFF_LAB = OFF_BL + (size_t)B_ * T_ * U1_ * 4;
static constexpr size_t OFF_HPK = OFF_LAB + (size_t)B_ * T_ * U1_ * 4;     // u64 [7][2][4][512] packets
static constexpr size_t OFF_JST = OFF_HPK + (size_t)7 * 4096 * 8;          // f32 [4][19520][4][2]

extern "C" void kernel_launch(void* const* d_in, const int* in_sizes, int n_in,
                              void* d_out, int out_size, void* d_ws, size_t ws_size,
                              hipStream_t stream) {
  (void)in_sizes; (void)n_in; (void)out_size; (void)ws_size;
  const float* inputs = (const float*)d_in[0];
  const int* inputs_length = (const int*)d_in[1];
  const int* targets = (const int*)d_in[2];
  const int* targets_length = (const int*)d_in[3];
  const float* enc_Wih = (const float*)d_in[4];
  const float* enc_Whh = (const float*)d_in[5];
  const float* enc_b = (const float*)d_in[6];
  const float* enc_proj_W = (const float*)d_in[7];
  const float* enc_proj_b = (const float*)d_in[8];
  const float* dec_emb = (const float*)d_in[9];
  const float* dec_Wih = (const float*)d_in[10];
  const float* dec_Whh = (const float*)d_in[11];
  const float* dec_b = (const float*)d_in[12];
  const float* dec_proj_W = (const float*)d_in[13];
  const float* dec_proj_b = (const float*)d_in[14];
  const float* j_fwd_W = (const float*)d_in[15];
  const float* j_fwd_b = (const float*)d_in[16];
  const float* j_proj_W = (const float*)d_in[17];
  const float* j_proj_b = (const float*)d_in[18];

  char* ws = (char*)d_ws;
  float* xg = (float*)(ws + OFF_XG);
  bf16* xa = (bf16*)(ws + OFF_XA);
  bf16* xb = (bf16*)(ws + OFF_XB);
  bf16* encb = (bf16*)(ws + OFF_ENC);
  float* eab = (float*)(ws + OFF_EA);
  bf16* demb = (bf16*)(ws + OFF_DEMB);
  float* dxg = (float*)(ws + OFF_DXG);
  bf16* dh = (bf16*)(ws + OFF_DH);
  bf16* decb = (bf16*)(ws + OFF_DEC);
  float* dab = (float*)(ws + OFF_DA);
  float* blank = (float*)(ws + OFF_BL);
  float* lab = (float*)(ws + OFF_LAB);
  u64* hpk = (u64*)(ws + OFF_HPK);
  float* jstats = (float*)(ws + OFF_JST);

  prep_kernel<<<600, 256, 0, stream>>>(inputs, xa);
  embed_kernel<<<520, 256, 0, stream>>>(dec_emb, targets, demb);

  // pre-scan GEMMs: decoder xg, then encoder layer-0 xg (both dirs)
  gemm_kernel<<<dim3(5, 32), 256, 0, stream>>>(demb, 512, dec_Wih, 512, dec_b,
                                               dxg, 1, G4_, B_ * U1_, 512);
  for (int dd = 0; dd < 2; ++dd) {
    gemm_kernel<<<dim3(19, 32), 256, 0, stream>>>(
        xa, 1024, enc_Wih + (size_t)dd * G4_ * 1024, 1024, enc_b + (size_t)dd * G4_,
        xg + (size_t)dd * B_ * T_ * G4_, 1, G4_, B_ * T_, 128);
  }
  // fused scan: dirs 0,1 = encoder layer 0; dir 2 = decoder (packet slots 0..2)
  scan_kernel<<<dim3(NW_, 3), 256, 0, stream>>>(
      xg, enc_Whh, inputs_length, 0, T_, 2, xb, 1024,
      2, dxg, dec_Whh, targets_length, 1, U1_, dh, 512,
      hpk);

  // decoder tail
  gemm_kernel<<<dim3(5, 8), 256, 0, stream>>>(dh, 512, dec_proj_W, 512, dec_proj_b,
                                              decb, 0, 512, B_ * U1_, 512);
  gemm_kernel<<<dim3(5, 8), 256, 0, stream>>>(decb, 512, j_fwd_W + 512, 1024, j_fwd_b,
                                              dab, 1, 512, B_ * U1_, 512);

  // encoder layers 1,2 (packet slots 3,4 and 5,6)
  bf16* xcur = xb;
  for (int lyr = 1; lyr < 3; ++lyr) {
    bf16* xnext = (xcur == xa) ? xb : xa;
    for (int dd = 0; dd < 2; ++dd) {
      gemm_kernel<<<dim3(19, 32), 256, 0, stream>>>(
          xcur, 1024,
          enc_Wih + (size_t)(lyr * 2 + dd) * G4_ * 1024, 1024,
          enc_b + (size_t)(lyr * 2 + dd) * G4_,
          xg + (size_t)dd * B_ * T_ * G4_, 1, G4_, B_ * T_, 1024);
    }
    scan_kernel<<<dim3(NW_, 2), 256, 0, stream>>>(
        xg, enc_Whh + (size_t)lyr * 2 * G4_ * H_,
        inputs_length, 0, T_, 2, xnext, 1024,
        -1, dxg, dec_Whh, targets_length, 1, U1_, dh, 512,
        hpk + (size_t)(3 + 2 * (lyr - 1)) * 4096);
    xcur = xnext;
  }
  gemm_kernel<<<dim3(19, 8), 256, 0, stream>>>(xcur, 1024, enc_proj_W, 1024, enc_proj_b,
                                               encb, 0, 512, B_ * T_, 1024);
  gemm_kernel<<<dim3(19, 8), 256, 0, stream>>>(encb, 512, j_fwd_W, 1024, (const float*)nullptr,
                                               eab, 1, 512, B_ * T_, 512);

  joint_kernel<<<dim3(NTILE_, 4, B_), 256, 0, stream>>>(eab, dab, j_proj_W, j_proj_b, targets,
                                                        blank, lab, jstats);
  finalize_kernel<<<(B_ * RPB_ + 255) / 256, 256, 0, stream>>>(jstats, blank, lab);
  loss_kernel<<<1, 256, 0, stream>>>(blank, lab, inputs_length, targets_length, (float*)d_out);
}